// Round 1
// baseline (4668.616 us; speedup 1.0000x reference)
//
#include <hip/hip_runtime.h>
#include <math.h>

// Transformer-XL tower, fp32 baseline.
// L=4, B=2, S=512, M=512, D=1024, H=16, DK=64, FF=4096, T=S+M=1024
#define CB  2
#define CS  512
#define CM  512
#define CD  1024
#define CH  16
#define CDK 64
#define CFF 4096
#define CL  4
#define CT  1024

// ---------------- positional encodings: pos[t][i]=sin(ang), pos[t][i+512]=cos(ang)
__global__ void pos_kernel(float* __restrict__ pos) {
    int idx = blockIdx.x * blockDim.x + threadIdx.x;   // T * D/2
    if (idx >= CT * (CD / 2)) return;
    int i = idx % (CD / 2);
    int t = idx / (CD / 2);
    float p = (float)(CT - 1 - t);
    // inv_freq = 10000^{-(2i)/D} = exp(-i * ln(10000)/512)
    float inv = __expf(-(float)i * (9.210340371976184f / 512.0f));
    float ang = p * inv;
    pos[(size_t)t * CD + i]            = sinf(ang);
    pos[(size_t)t * CD + i + CD / 2]   = cosf(ang);
}

// ---------------- kv = concat(memory[l], h) along time
__global__ void concat_kernel(const float* __restrict__ mem, const float* __restrict__ h,
                              float* __restrict__ kv) {
    int idx = blockIdx.x * blockDim.x + threadIdx.x;   // over B*T*D/4 float4s
    const int D4 = CD / 4;
    if (idx >= CB * CT * D4) return;
    int d4 = idx % D4;
    int bt = idx / D4;
    int t = bt % CT;
    int b = bt / CT;
    float4 val;
    if (t < CM) val = ((const float4*)mem)[((size_t)(b * CM + t)) * D4 + d4];
    else        val = ((const float4*)h)  [((size_t)(b * CS + (t - CM))) * D4 + d4];
    ((float4*)kv)[idx] = val;
}

// ---------------- classic fp32 SGEMM: C[M,N] = A[M,K] @ B[K,N]
// variant: 0 plain, 1 *0.125, 2 +bias relu, 3 +bias
__global__ __launch_bounds__(256)
void sgemm(const float* __restrict__ A, const float* __restrict__ B,
           float* __restrict__ C, int Mr, int Nc, int Kd,
           const float* __restrict__ bias, int variant)
{
    __shared__ __align__(16) float As[16][68];   // As[k][m], padded
    __shared__ __align__(16) float Bs[16][68];   // Bs[k][n], padded
    const int tid  = threadIdx.x;
    const int row0 = blockIdx.y * 64;
    const int col0 = blockIdx.x * 64;
    const int tx = tid & 15, ty = tid >> 4;
    const int ar = tid >> 2, ac4 = tid & 3;     // A tile: 64 rows x 4 float4
    const int br = tid >> 4, bc4 = tid & 15;    // B tile: 16 rows x 16 float4
    float acc[4][4] = {};
    for (int k0 = 0; k0 < Kd; k0 += 16) {
        float4 av = *(const float4*)&A[(size_t)(row0 + ar) * Kd + k0 + ac4 * 4];
        float4 bv = *(const float4*)&B[(size_t)(k0 + br) * Nc + col0 + bc4 * 4];
        __syncthreads();
        As[ac4 * 4 + 0][ar] = av.x; As[ac4 * 4 + 1][ar] = av.y;
        As[ac4 * 4 + 2][ar] = av.z; As[ac4 * 4 + 3][ar] = av.w;
        *(float4*)&Bs[br][bc4 * 4] = bv;
        __syncthreads();
        #pragma unroll
        for (int kk = 0; kk < 16; ++kk) {
            float4 a4 = *(const float4*)&As[kk][ty * 4];
            float4 b4 = *(const float4*)&Bs[kk][tx * 4];
            float aa[4] = {a4.x, a4.y, a4.z, a4.w};
            float bb[4] = {b4.x, b4.y, b4.z, b4.w};
            #pragma unroll
            for (int i = 0; i < 4; ++i)
                #pragma unroll
                for (int j = 0; j < 4; ++j)
                    acc[i][j] += aa[i] * bb[j];
        }
    }
    float4 bvv = make_float4(0.f, 0.f, 0.f, 0.f);
    if (variant >= 2) bvv = *(const float4*)&bias[col0 + tx * 4];
    #pragma unroll
    for (int i = 0; i < 4; ++i) {
        float4 c = make_float4(acc[i][0], acc[i][1], acc[i][2], acc[i][3]);
        if (variant == 1) { c.x *= 0.125f; c.y *= 0.125f; c.z *= 0.125f; c.w *= 0.125f; }
        if (variant >= 2) { c.x += bvv.x; c.y += bvv.y; c.z += bvv.z; c.w += bvv.w; }
        if (variant == 2) {
            c.x = fmaxf(c.x, 0.f); c.y = fmaxf(c.y, 0.f);
            c.z = fmaxf(c.z, 0.f); c.w = fmaxf(c.w, 0.f);
        }
        *(float4*)&C[(size_t)(row0 + ty * 4 + i) * Nc + col0 + tx * 4] = c;
    }
}

// ---------------- fused rel-attention (flash-style online softmax)
// score(i,j) = (q_i+rwb)·k_j + (q_i+rrb)·r_{j+S-1-i},  valid j <= i+M
// block: 32 queries for one (b,h); 256 threads; thread = (row il=tid/8, slot s=tid%8)
__global__ __launch_bounds__(256)
void attn_kernel(const float* __restrict__ qm, const float* __restrict__ km,
                 const float* __restrict__ vm, const float* __restrict__ rm,
                 const float* __restrict__ rwb, const float* __restrict__ rrb,
                 float* __restrict__ outm)
{
    const int q0 = blockIdx.x * 32;
    const int hh = blockIdx.y;
    const int bb = blockIdx.z;
    __shared__ __align__(16) float qw[32][68];
    __shared__ __align__(16) float qr[32][68];
    __shared__ __align__(16) float ks[64][68];
    __shared__ __align__(16) float vs[64][64];
    __shared__ __align__(16) float ps[32][68];
    const int tid = threadIdx.x;

    // stage q tile + both bias-added variants
    #pragma unroll
    for (int rep = 0; rep < 2; ++rep) {
        int lin = rep * 256 + tid;            // 32 rows x 16 float4
        int i = lin >> 4, c4 = lin & 15;
        float4 qv = *(const float4*)&qm[((size_t)(bb * CS + q0 + i)) * CD + hh * CDK + c4 * 4];
        float4 bw = *(const float4*)&rwb[hh * CDK + c4 * 4];
        float4 br = *(const float4*)&rrb[hh * CDK + c4 * 4];
        qw[i][c4 * 4 + 0] = qv.x + bw.x; qw[i][c4 * 4 + 1] = qv.y + bw.y;
        qw[i][c4 * 4 + 2] = qv.z + bw.z; qw[i][c4 * 4 + 3] = qv.w + bw.w;
        qr[i][c4 * 4 + 0] = qv.x + br.x; qr[i][c4 * 4 + 1] = qv.y + br.y;
        qr[i][c4 * 4 + 2] = qv.z + br.z; qr[i][c4 * 4 + 3] = qv.w + br.w;
    }

    const int il = tid >> 3;
    const int s  = tid & 7;
    const int ig = q0 + il;
    float m_run = -1e30f, l_run = 0.f;
    float o[8] = {0, 0, 0, 0, 0, 0, 0, 0};   // dims d = s*8 + dd
    const int jmax = q0 + 31 + CM;
    const int ntiles = (jmax + 64) >> 6;

    for (int tt = 0; tt < ntiles; ++tt) {
        const int j0 = tt * 64;
        __syncthreads();                      // prev PV done before overwriting ks/vs
        #pragma unroll
        for (int rep = 0; rep < 4; ++rep) {
            int lin = rep * 256 + tid;        // 64 rows x 16 float4
            int jr = lin >> 4, c4 = lin & 15;
            size_t gofs = ((size_t)(bb * CT + j0 + jr)) * CD + hh * CDK + c4 * 4;
            *(float4*)&ks[jr][c4 * 4] = *(const float4*)&km[gofs];
            *(float4*)&vs[jr][c4 * 4] = *(const float4*)&vm[gofs];
        }
        __syncthreads();

        float acc[8];
        #pragma unroll
        for (int jj = 0; jj < 8; ++jj) acc[jj] = 0.f;
        for (int db = 0; db < 4; ++db) {       // 16-wide d blocks, q cached in regs
            const int dbase = db * 16;
            float4 xq0 = *(const float4*)&qw[il][dbase + 0];
            float4 xq1 = *(const float4*)&qw[il][dbase + 4];
            float4 xq2 = *(const float4*)&qw[il][dbase + 8];
            float4 xq3 = *(const float4*)&qw[il][dbase + 12];
            float4 yq0 = *(const float4*)&qr[il][dbase + 0];
            float4 yq1 = *(const float4*)&qr[il][dbase + 4];
            float4 yq2 = *(const float4*)&qr[il][dbase + 8];
            float4 yq3 = *(const float4*)&qr[il][dbase + 12];
            #pragma unroll
            for (int jj = 0; jj < 8; ++jj) {
                const int jl = s + jj * 8;
                const int j  = j0 + jl;
                if (j <= ig + CM) {
                    const int trel = j + (CS - 1) - ig;   // in [0, T-1] for valid j
                    const float* rrow = &rm[(size_t)trel * CD + hh * CDK + dbase];
                    float4 xk0 = *(const float4*)&ks[jl][dbase + 0];
                    float4 xk1 = *(const float4*)&ks[jl][dbase + 4];
                    float4 xk2 = *(const float4*)&ks[jl][dbase + 8];
                    float4 xk3 = *(const float4*)&ks[jl][dbase + 12];
                    float4 yr0 = *(const float4*)&rrow[0];
                    float4 yr1 = *(const float4*)&rrow[4];
                    float4 yr2 = *(const float4*)&rrow[8];
                    float4 yr3 = *(const float4*)&rrow[12];
                    acc[jj] += xq0.x * xk0.x + xq0.y * xk0.y + xq0.z * xk0.z + xq0.w * xk0.w
                             + xq1.x * xk1.x + xq1.y * xk1.y + xq1.z * xk1.z + xq1.w * xk1.w
                             + xq2.x * xk2.x + xq2.y * xk2.y + xq2.z * xk2.z + xq2.w * xk2.w
                             + xq3.x * xk3.x + xq3.y * xk3.y + xq3.z * xk3.z + xq3.w * xk3.w
                             + yq0.x * yr0.x + yq0.y * yr0.y + yq0.z * yr0.z + yq0.w * yr0.w
                             + yq1.x * yr1.x + yq1.y * yr1.y + yq1.z * yr1.z + yq1.w * yr1.w
                             + yq2.x * yr2.x + yq2.y * yr2.y + yq2.z * yr2.z + yq2.w * yr2.w
                             + yq3.x * yr3.x + yq3.y * yr3.y + yq3.z * yr3.z + yq3.w * yr3.w;
                }
            }
        }

        float lm = -1e30f;
        float sc[8];
        #pragma unroll
        for (int jj = 0; jj < 8; ++jj) {
            const int j = j0 + s + jj * 8;
            sc[jj] = (j <= ig + CM) ? acc[jj] : -1e30f;
            lm = fmaxf(lm, sc[jj]);
        }
        #pragma unroll
        for (int off = 1; off < 8; off <<= 1) lm = fmaxf(lm, __shfl_xor(lm, off));
        const float m_new = fmaxf(m_run, lm);
        const float scale = __expf(m_run - m_new);
        float ts = 0.f;
        #pragma unroll
        for (int jj = 0; jj < 8; ++jj) {
            float p = __expf(sc[jj] - m_new);
            ps[il][s + jj * 8] = p;
            ts += p;
        }
        #pragma unroll
        for (int off = 1; off < 8; off <<= 1) ts += __shfl_xor(ts, off);
        l_run = l_run * scale + ts;
        m_run = m_new;
        #pragma unroll
        for (int dd = 0; dd < 8; ++dd) o[dd] *= scale;
        __syncthreads();                      // ps visible to whole row group

        #pragma unroll 4
        for (int jl = 0; jl < 64; ++jl) {
            const float p = ps[il][jl];
            float4 v0 = *(const float4*)&vs[jl][s * 8];
            float4 v1 = *(const float4*)&vs[jl][s * 8 + 4];
            o[0] += p * v0.x; o[1] += p * v0.y; o[2] += p * v0.z; o[3] += p * v0.w;
            o[4] += p * v1.x; o[5] += p * v1.y; o[6] += p * v1.z; o[7] += p * v1.w;
        }
    }

    const float invl = 1.0f / l_run;
    float4 w0 = make_float4(o[0] * invl, o[1] * invl, o[2] * invl, o[3] * invl);
    float4 w1 = make_float4(o[4] * invl, o[5] * invl, o[6] * invl, o[7] * invl);
    size_t obase = ((size_t)(bb * CS + ig)) * CD + hh * CDK + s * 8;
    *(float4*)&outm[obase]     = w0;
    *(float4*)&outm[obase + 4] = w1;
}

// ---------------- residual + layernorm: out = LN(a + b) * g + beta, row length 1024
__global__ __launch_bounds__(256)
void ln_kernel(const float* __restrict__ a, const float* __restrict__ bsrc,
               const float* __restrict__ g, const float* __restrict__ beta,
               float* __restrict__ out)
{
    const int row = blockIdx.x;
    const int tid = threadIdx.x;
    const size_t base = (size_t)row * CD;
    float4 xa = *(const float4*)&a[base + tid * 4];
    float4 xb = *(const float4*)&bsrc[base + tid * 4];
    float x0 = xa.x + xb.x, x1 = xa.y + xb.y, x2 = xa.z + xb.z, x3 = xa.w + xb.w;
    float sum = x0 + x1 + x2 + x3;
    float sq  = x0 * x0 + x1 * x1 + x2 * x2 + x3 * x3;
    #pragma unroll
    for (int off = 1; off < 64; off <<= 1) {
        sum += __shfl_xor(sum, off);
        sq  += __shfl_xor(sq, off);
    }
    __shared__ float ssum[4], ssq[4];
    const int wid = tid >> 6;
    if ((tid & 63) == 0) { ssum[wid] = sum; ssq[wid] = sq; }
    __syncthreads();
    sum = ssum[0] + ssum[1] + ssum[2] + ssum[3];
    sq  = ssq[0] + ssq[1] + ssq[2] + ssq[3];
    const float mean = sum * (1.0f / CD);
    const float var  = sq * (1.0f / CD) - mean * mean;
    const float rstd = rsqrtf(var + 1e-5f);
    float4 gv = *(const float4*)&g[tid * 4];
    float4 bv = *(const float4*)&beta[tid * 4];
    float4 r;
    r.x = (x0 - mean) * rstd * gv.x + bv.x;
    r.y = (x1 - mean) * rstd * gv.y + bv.y;
    r.z = (x2 - mean) * rstd * gv.z + bv.z;
    r.w = (x3 - mean) * rstd * gv.w + bv.w;
    *(float4*)&out[base + tid * 4] = r;
}

extern "C" void kernel_launch(void* const* d_in, const int* in_sizes, int n_in,
                              void* d_out, int out_size, void* d_ws, size_t ws_size,
                              hipStream_t stream) {
    const float* x    = (const float*)d_in[0];
    const float* memL = (const float*)d_in[1];
    const float* Wq   = (const float*)d_in[2];
    const float* Wk   = (const float*)d_in[3];
    const float* Wv   = (const float*)d_in[4];
    const float* Wr   = (const float*)d_in[5];
    const float* Wo   = (const float*)d_in[6];
    const float* rwb  = (const float*)d_in[7];
    const float* rrb  = (const float*)d_in[8];
    const float* ln1g = (const float*)d_in[9];
    const float* ln1b = (const float*)d_in[10];
    const float* ln2g = (const float*)d_in[11];
    const float* ln2b = (const float*)d_in[12];
    const float* W1   = (const float*)d_in[13];
    const float* b1   = (const float*)d_in[14];
    const float* W2   = (const float*)d_in[15];
    const float* b2   = (const float*)d_in[16];

    float* ws = (float*)d_ws;
    const size_t BSD = (size_t)CB * CS * CD;   // 1,048,576
    const size_t BTD = (size_t)CB * CT * CD;   // 2,097,152
    const size_t TD  = (size_t)CT * CD;        // 1,048,576
    float* h    = ws;
    float* kv   = h + BSD;
    float* qb   = kv + BTD;
    float* kb   = qb + BSD;
    float* vb   = kb + BTD;
    float* rb   = vb + BTD;
    float* posb = rb + TD;
    float* attn = posb + TD;
    float* tmp  = attn + BSD;
    float* ff1  = tmp + BSD;                   // B*S*FF = 4,194,304
    // total 16,777,216 floats = 64 MB

    hipMemcpyAsync(h, x, BSD * sizeof(float), hipMemcpyDeviceToDevice, stream);
    pos_kernel<<<(CT * (CD / 2)) / 256, 256, 0, stream>>>(posb);

    for (int l = 0; l < CL; ++l) {
        concat_kernel<<<(CB * CT * CD / 4) / 256, 256, 0, stream>>>(
            memL + (size_t)l * CB * CM * CD, h, kv);
        // projections
        sgemm<<<dim3(CD / 64, CB * CS / 64), 256, 0, stream>>>(
            h, Wq + (size_t)l * CD * CD, qb, CB * CS, CD, CD, nullptr, 1);   // *0.125
        sgemm<<<dim3(CD / 64, CB * CT / 64), 256, 0, stream>>>(
            kv, Wk + (size_t)l * CD * CD, kb, CB * CT, CD, CD, nullptr, 0);
        sgemm<<<dim3(CD / 64, CB * CT / 64), 256, 0, stream>>>(
            kv, Wv + (size_t)l * CD * CD, vb, CB * CT, CD, CD, nullptr, 0);
        sgemm<<<dim3(CD / 64, CT / 64), 256, 0, stream>>>(
            posb, Wr + (size_t)l * CD * CD, rb, CT, CD, CD, nullptr, 0);
        // fused relative attention
        attn_kernel<<<dim3(CS / 32, CH, CB), 256, 0, stream>>>(
            qb, kb, vb, rb,
            rwb + (size_t)l * CH * CDK, rrb + (size_t)l * CH * CDK, attn);
        // merge + LN1
        sgemm<<<dim3(CD / 64, CB * CS / 64), 256, 0, stream>>>(
            attn, Wo + (size_t)l * CD * CD, tmp, CB * CS, CD, CD, nullptr, 0);
        ln_kernel<<<CB * CS, 256, 0, stream>>>(
            h, tmp, ln1g + (size_t)l * CD, ln1b + (size_t)l * CD, h);
        // FF + LN2
        sgemm<<<dim3(CFF / 64, CB * CS / 64), 256, 0, stream>>>(
            h, W1 + (size_t)l * CD * CFF, ff1, CB * CS, CFF, CD, b1 + (size_t)l * CFF, 2);
        sgemm<<<dim3(CD / 64, CB * CS / 64), 256, 0, stream>>>(
            ff1, W2 + (size_t)l * CFF * CD, tmp, CB * CS, CD, CFF, b2 + (size_t)l * CD, 3);
        ln_kernel<<<CB * CS, 256, 0, stream>>>(
            h, tmp, ln2g + (size_t)l * CD, ln2b + (size_t)l * CD, h);
    }
    hipMemcpyAsync(d_out, h, BSD * sizeof(float), hipMemcpyDeviceToDevice, stream);
}

// Round 2
// 1712.371 us; speedup vs baseline: 2.7264x; 2.7264x over previous
//
#include <hip/hip_runtime.h>
#include <math.h>

// Transformer-XL tower. bf16 MFMA GEMMs + fp32 flash attention with LDS r-band.
// L=4, B=2, S=512, M=512, D=1024, H=16, DK=64, FF=4096, T=S+M=1024
#define CB  2
#define CS  512
#define CM  512
#define CD  1024
#define CH  16
#define CDK 64
#define CFF 4096
#define CL  4
#define CT  1024

using short8 = __attribute__((ext_vector_type(8))) short;
using f32x4  = __attribute__((ext_vector_type(4))) float;

__device__ __forceinline__ ushort f2bf(float x) {
    union { float f; unsigned int u; } c; c.f = x;
    unsigned int u = c.u + 0x7FFFu + ((c.u >> 16) & 1u);
    return (ushort)(u >> 16);
}
__device__ __forceinline__ float bf2f(ushort h) {
    union { unsigned int u; float f; } c; c.u = ((unsigned int)h) << 16;
    return c.f;
}

// async global->LDS, 16B per lane; dest = wave-uniform base + lane*16
#define GLD16(gsrc, ldst) \
    __builtin_amdgcn_global_load_lds((const __attribute__((address_space(1))) void*)(gsrc), \
                                     (__attribute__((address_space(3))) void*)(ldst), 16, 0, 0)

// ---------------- positional encodings -> bf16 [T][D]
__global__ void pos_kernel(ushort* __restrict__ pos) {
    int idx = blockIdx.x * blockDim.x + threadIdx.x;   // T * D/2
    if (idx >= CT * (CD / 2)) return;
    int i = idx % (CD / 2);
    int t = idx / (CD / 2);
    float p = (float)(CT - 1 - t);
    float inv = __expf(-(float)i * (9.210340371976184f / 512.0f));
    float ang = p * inv;
    pos[(size_t)t * CD + i]          = f2bf(sinf(ang));
    pos[(size_t)t * CD + i + CD / 2] = f2bf(cosf(ang));
}

// ---------------- kv_bf16 = concat(memory[l], h) along time
__global__ void concat_bf16_kernel(const float* __restrict__ mem, const float* __restrict__ h,
                                   ushort* __restrict__ kv) {
    int idx = blockIdx.x * blockDim.x + threadIdx.x;   // B*T*D/8
    const int D8 = CD / 8;
    if (idx >= CB * CT * D8) return;
    int d8 = idx % D8;
    int bt = idx / D8;
    int t = bt % CT;
    int b = bt / CT;
    const float* src = (t < CM) ? &mem[((size_t)(b * CM + t)) * CD + d8 * 8]
                                : &h[((size_t)(b * CS + (t - CM))) * CD + d8 * 8];
    float4 a = *(const float4*)src;
    float4 c = *(const float4*)(src + 4);
    union { ushort us[8]; uint4 q; } pk;
    pk.us[0] = f2bf(a.x); pk.us[1] = f2bf(a.y); pk.us[2] = f2bf(a.z); pk.us[3] = f2bf(a.w);
    pk.us[4] = f2bf(c.x); pk.us[5] = f2bf(c.y); pk.us[6] = f2bf(c.z); pk.us[7] = f2bf(c.w);
    ((uint4*)kv)[idx] = pk.q;
}

// ---------------- elementwise f32 -> bf16 (n8 = count/8)
__global__ void cvt_bf16_kernel(const float* __restrict__ in, ushort* __restrict__ out, int n8) {
    int i = blockIdx.x * blockDim.x + threadIdx.x;
    if (i >= n8) return;
    float4 a = ((const float4*)in)[i * 2];
    float4 c = ((const float4*)in)[i * 2 + 1];
    union { ushort us[8]; uint4 q; } pk;
    pk.us[0] = f2bf(a.x); pk.us[1] = f2bf(a.y); pk.us[2] = f2bf(a.z); pk.us[3] = f2bf(a.w);
    pk.us[4] = f2bf(c.x); pk.us[5] = f2bf(c.y); pk.us[6] = f2bf(c.z); pk.us[7] = f2bf(c.w);
    ((uint4*)out)[i] = pk.q;
}

// ---------------- transpose+convert: in f32 [K][N] -> out bf16 [N][K]
__global__ __launch_bounds__(256)
void transpose_cvt(const float* __restrict__ in, ushort* __restrict__ out, int Kd, int Nc) {
    __shared__ __align__(16) float t[64][68];
    const int n0 = blockIdx.x * 64, k0 = blockIdx.y * 64;
    const int tid = threadIdx.x;
    #pragma unroll
    for (int rep = 0; rep < 4; ++rep) {
        int lin = rep * 256 + tid;         // 64 rows x 16 float4
        int r = lin >> 4, c4 = lin & 15;
        float4 v = *(const float4*)&in[(size_t)(k0 + r) * Nc + n0 + c4 * 4];
        *(float4*)&t[r][c4 * 4] = v;       // 68*4=272B stride, 16B aligned
    }
    __syncthreads();
    #pragma unroll
    for (int rep = 0; rep < 2; ++rep) {
        int lin = rep * 256 + tid;         // 64 n-rows x 8 k-chunks
        int n = lin >> 3, kc = lin & 7;
        union { ushort us[8]; uint4 q; } pk;
        #pragma unroll
        for (int j = 0; j < 8; ++j) pk.us[j] = f2bf(t[kc * 8 + j][n]);
        *(uint4*)&out[(size_t)(n0 + n) * Kd + k0 + kc * 8] = pk.q;
    }
}

// ---------------- bf16 MFMA GEMM: C[M,N] = A[M,K] @ Bt[N,K]^T  (m97 structure)
// 128x128 tile, BK=32, 4 waves (2x2), each wave 64x64 = 4x4 frags of 16x16x32
__global__ __launch_bounds__(256)
void gemm_bf16(const ushort* __restrict__ A, const ushort* __restrict__ Bt,
               float* __restrict__ Cf, ushort* __restrict__ Cbf,
               int Mr, int Nc, int Kd, const float* __restrict__ bias,
               float scale, int relu)
{
    __shared__ __align__(16) ushort As[128 * 32];
    __shared__ __align__(16) ushort Bs[128 * 32];
    const int tid  = threadIdx.x;
    const int lane = tid & 63, w = tid >> 6;
    const int wr = w >> 1, wc = w & 1;
    const int row0 = blockIdx.y * 128, col0 = blockIdx.x * 128;
    const ushort* Ab = A  + (size_t)row0 * Kd;
    const ushort* Bb = Bt + (size_t)col0 * Kd;
    f32x4 acc[4][4];
    #pragma unroll
    for (int m = 0; m < 4; ++m)
        #pragma unroll
        for (int n = 0; n < 4; ++n) acc[m][n] = (f32x4){0.f, 0.f, 0.f, 0.f};

    for (int k0 = 0; k0 < Kd; k0 += 32) {
        __syncthreads();
        #pragma unroll
        for (int c = 0; c < 2; ++c) {
            const int linw = (c * 4 + w) * 64;       // wave-base 16B-chunk index
            const int lin  = linw + lane;
            const int row = lin >> 2, kc = lin & 3;  // 128 rows x 4 chunks of 8 bf16
            GLD16(Ab + (size_t)row * Kd + k0 + kc * 8, As + linw * 8);
            GLD16(Bb + (size_t)row * Kd + k0 + kc * 8, Bs + linw * 8);
        }
        __syncthreads();   // drains vmcnt(0) -> LDS ready
        short8 af[4], bfr[4];
        #pragma unroll
        for (int m = 0; m < 4; ++m)
            af[m] = *(const short8*)&As[(wr * 64 + m * 16 + (lane & 15)) * 32 + (lane >> 4) * 8];
        #pragma unroll
        for (int n = 0; n < 4; ++n)
            bfr[n] = *(const short8*)&Bs[(wc * 64 + n * 16 + (lane & 15)) * 32 + (lane >> 4) * 8];
        #pragma unroll
        for (int m = 0; m < 4; ++m)
            #pragma unroll
            for (int n = 0; n < 4; ++n)
                acc[m][n] = __builtin_amdgcn_mfma_f32_16x16x32_bf16(af[m], bfr[n], acc[m][n], 0, 0, 0);
    }

    // epilogue: row = row0+wr*64+m*16+(lane>>4)*4+reg, col = col0+wc*64+n*16+(lane&15)
    const int colbase = col0 + wc * 64 + (lane & 15);
    const int rowbase = row0 + wr * 64 + ((lane >> 4) << 2);
    #pragma unroll
    for (int n = 0; n < 4; ++n) {
        const int col = colbase + n * 16;
        const float bv = bias ? bias[col] : 0.f;
        #pragma unroll
        for (int m = 0; m < 4; ++m) {
            #pragma unroll
            for (int r = 0; r < 4; ++r) {
                const int row = rowbase + m * 16 + r;
                float v = acc[m][n][r] * scale + bv;
                if (relu) v = fmaxf(v, 0.f);
                if (Cf)  Cf[(size_t)row * Nc + col] = v;
                if (Cbf) Cbf[(size_t)row * Nc + col] = f2bf(v);
            }
        }
    }
}

// ---------------- fused rel-attention (flash-style), r-band staged in LDS (bf16)
// score(i,j) = (q_i+rwb)·k_j + (q_i+rrb)·r_{j+S-1-i},  valid j <= i+M
// k from kvo cols [0,1024), v from cols [1024,2048). Output bf16.
__global__ __launch_bounds__(256)
void attn_kernel(const float* __restrict__ qm, const float* __restrict__ kvo,
                 const float* __restrict__ rm,
                 const float* __restrict__ rwb, const float* __restrict__ rrb,
                 ushort* __restrict__ outm)
{
    const int q0 = blockIdx.x * 32;
    const int hh = blockIdx.y;
    const int bb = blockIdx.z;
    __shared__ __align__(16) float qw[32][68];
    __shared__ __align__(16) float qr[32][68];
    __shared__ __align__(16) float ks[64][68];
    __shared__ __align__(16) float vs[64][64];
    __shared__ __align__(16) float ps[32][68];
    __shared__ __align__(16) ushort rs[96][72];
    const int tid = threadIdx.x;

    #pragma unroll
    for (int rep = 0; rep < 2; ++rep) {
        int lin = rep * 256 + tid;            // 32 rows x 16 float4
        int i = lin >> 4, c4 = lin & 15;
        float4 qv = *(const float4*)&qm[((size_t)(bb * CS + q0 + i)) * CD + hh * CDK + c4 * 4];
        float4 bw = *(const float4*)&rwb[hh * CDK + c4 * 4];
        float4 br = *(const float4*)&rrb[hh * CDK + c4 * 4];
        qw[i][c4 * 4 + 0] = qv.x + bw.x; qw[i][c4 * 4 + 1] = qv.y + bw.y;
        qw[i][c4 * 4 + 2] = qv.z + bw.z; qw[i][c4 * 4 + 3] = qv.w + bw.w;
        qr[i][c4 * 4 + 0] = qv.x + br.x; qr[i][c4 * 4 + 1] = qv.y + br.y;
        qr[i][c4 * 4 + 2] = qv.z + br.z; qr[i][c4 * 4 + 3] = qv.w + br.w;
    }

    const int il = tid >> 3;
    const int s  = tid & 7;
    const int ig = q0 + il;
    float m_run = -1e30f, l_run = 0.f;
    float o[8] = {0, 0, 0, 0, 0, 0, 0, 0};
    const int jmax = q0 + 31 + CM;
    const int ntiles = (jmax + 64) >> 6;

    for (int tt = 0; tt < ntiles; ++tt) {
        const int j0 = tt * 64;
        const int tbase = j0 + (CS - 1) - q0 - 31;     // r-window base
        __syncthreads();
        #pragma unroll
        for (int rep = 0; rep < 4; ++rep) {
            int lin = rep * 256 + tid;        // 64 rows x 16 float4
            int jr = lin >> 4, c4 = lin & 15;
            size_t gofs = ((size_t)(bb * CT + j0 + jr)) * 2048 + hh * CDK + c4 * 4;
            *(float4*)&ks[jr][c4 * 4] = *(const float4*)&kvo[gofs];
            *(float4*)&vs[jr][c4 * 4] = *(const float4*)&kvo[gofs + 1024];
        }
        #pragma unroll
        for (int rep = 0; rep < 3; ++rep) {
            int lin = rep * 256 + tid;        // 96 rows x 8 chunks of 8
            int rrw = lin >> 3, c8 = lin & 7;
            int t = tbase + rrw;
            t = t < 0 ? 0 : (t > CT - 1 ? CT - 1 : t);
            const float* src = &rm[(size_t)t * CD + hh * CDK + c8 * 8];
            float4 a = *(const float4*)src;
            float4 b = *(const float4*)(src + 4);
            union { ushort us[8]; uint4 q; } pk;
            pk.us[0] = f2bf(a.x); pk.us[1] = f2bf(a.y); pk.us[2] = f2bf(a.z); pk.us[3] = f2bf(a.w);
            pk.us[4] = f2bf(b.x); pk.us[5] = f2bf(b.y); pk.us[6] = f2bf(b.z); pk.us[7] = f2bf(b.w);
            *(uint4*)&rs[rrw][c8 * 8] = pk.q;
        }
        __syncthreads();

        float acc[8];
        #pragma unroll
        for (int jj = 0; jj < 8; ++jj) acc[jj] = 0.f;
        for (int db = 0; db < 4; ++db) {
            const int dbase = db * 16;
            float4 xq0 = *(const float4*)&qw[il][dbase + 0];
            float4 xq1 = *(const float4*)&qw[il][dbase + 4];
            float4 xq2 = *(const float4*)&qw[il][dbase + 8];
            float4 xq3 = *(const float4*)&qw[il][dbase + 12];
            float4 yq0 = *(const float4*)&qr[il][dbase + 0];
            float4 yq1 = *(const float4*)&qr[il][dbase + 4];
            float4 yq2 = *(const float4*)&qr[il][dbase + 8];
            float4 yq3 = *(const float4*)&qr[il][dbase + 12];
            #pragma unroll
            for (int jj = 0; jj < 8; ++jj) {
                const int jl = s + jj * 8;
                const int j  = j0 + jl;
                if (j <= ig + CM) {
                    const int idx = jl - il + 31;       // r-band row, in [0,94]
                    const ushort* rp = &rs[idx][dbase];
                    short8 rv0 = *(const short8*)rp;
                    short8 rv1 = *(const short8*)(rp + 8);
                    float4 xk0 = *(const float4*)&ks[jl][dbase + 0];
                    float4 xk1 = *(const float4*)&ks[jl][dbase + 4];
                    float4 xk2 = *(const float4*)&ks[jl][dbase + 8];
                    float4 xk3 = *(const float4*)&ks[jl][dbase + 12];
                    float4 yr0 = make_float4(bf2f((ushort)rv0[0]), bf2f((ushort)rv0[1]),
                                             bf2f((ushort)rv0[2]), bf2f((ushort)rv0[3]));
                    float4 yr1 = make_float4(bf2f((ushort)rv0[4]), bf2f((ushort)rv0[5]),
                                             bf2f((ushort)rv0[6]), bf2f((ushort)rv0[7]));
                    float4 yr2 = make_float4(bf2f((ushort)rv1[0]), bf2f((ushort)rv1[1]),
                                             bf2f((ushort)rv1[2]), bf2f((ushort)rv1[3]));
                    float4 yr3 = make_float4(bf2f((ushort)rv1[4]), bf2f((ushort)rv1[5]),
                                             bf2f((ushort)rv1[6]), bf2f((ushort)rv1[7]));
                    acc[jj] += xq0.x * xk0.x + xq0.y * xk0.y + xq0.z * xk0.z + xq0.w * xk0.w
                             + xq1.x * xk1.x + xq1.y * xk1.y + xq1.z * xk1.z + xq1.w * xk1.w
                             + xq2.x * xk2.x + xq2.y * xk2.y + xq2.z * xk2.z + xq2.w * xk2.w
                             + xq3.x * xk3.x + xq3.y * xk3.y + xq3.z * xk3.z + xq3.w * xk3.w
                             + yq0.x * yr0.x + yq0.y * yr0.y + yq0.z * yr0.z + yq0.w * yr0.w
                             + yq1.x * yr1.x + yq1.y * yr1.y + yq1.z * yr1.z + yq1.w * yr1.w
                             + yq2.x * yr2.x + yq2.y * yr2.y + yq2.z * yr2.z + yq2.w * yr2.w
                             + yq3.x * yr3.x + yq3.y * yr3.y + yq3.z * yr3.z + yq3.w * yr3.w;
                }
            }
        }

        float lm = -1e30f;
        float sc[8];
        #pragma unroll
        for (int jj = 0; jj < 8; ++jj) {
            const int j = j0 + s + jj * 8;
            sc[jj] = (j <= ig + CM) ? acc[jj] : -1e30f;
            lm = fmaxf(lm, sc[jj]);
        }
        #pragma unroll
        for (int off = 1; off < 8; off <<= 1) lm = fmaxf(lm, __shfl_xor(lm, off));
        const float m_new = fmaxf(m_run, lm);
        const float scale = __expf(m_run - m_new);
        float ts = 0.f;
        #pragma unroll
        for (int jj = 0; jj < 8; ++jj) {
            float p = __expf(sc[jj] - m_new);
            ps[il][s + jj * 8] = p;
            ts += p;
        }
        #pragma unroll
        for (int off = 1; off < 8; off <<= 1) ts += __shfl_xor(ts, off);
        l_run = l_run * scale + ts;
        m_run = m_new;
        #pragma unroll
        for (int dd = 0; dd < 8; ++dd) o[dd] *= scale;
        __syncthreads();

        #pragma unroll 4
        for (int jl = 0; jl < 64; ++jl) {
            const float p = ps[il][jl];
            float4 v0 = *(const float4*)&vs[jl][s * 8];
            float4 v1 = *(const float4*)&vs[jl][s * 8 + 4];
            o[0] += p * v0.x; o[1] += p * v0.y; o[2] += p * v0.z; o[3] += p * v0.w;
            o[4] += p * v1.x; o[5] += p * v1.y; o[6] += p * v1.z; o[7] += p * v1.w;
        }
    }

    const float invl = 1.0f / l_run;
    union { ushort us[8]; uint4 q; } pk;
    #pragma unroll
    for (int dd = 0; dd < 8; ++dd) pk.us[dd] = f2bf(o[dd] * invl);
    size_t obase = ((size_t)(bb * CS + ig)) * CD + hh * CDK + s * 8;
    *(uint4*)&outm[obase] = pk.q;
}

// ---------------- residual + layernorm, dual output (f32 + optional bf16)
__global__ __launch_bounds__(256)
void ln_kernel(const float* __restrict__ a, const float* __restrict__ bsrc,
               const float* __restrict__ g, const float* __restrict__ beta,
               float* __restrict__ out, ushort* __restrict__ outbf)
{
    const int row = blockIdx.x;
    const int tid = threadIdx.x;
    const size_t base = (size_t)row * CD;
    float4 xa = *(const float4*)&a[base + tid * 4];
    float4 xb = *(const float4*)&bsrc[base + tid * 4];
    float x0 = xa.x + xb.x, x1 = xa.y + xb.y, x2 = xa.z + xb.z, x3 = xa.w + xb.w;
    float sum = x0 + x1 + x2 + x3;
    float sq  = x0 * x0 + x1 * x1 + x2 * x2 + x3 * x3;
    #pragma unroll
    for (int off = 1; off < 64; off <<= 1) {
        sum += __shfl_xor(sum, off);
        sq  += __shfl_xor(sq, off);
    }
    __shared__ float ssum[4], ssq[4];
    const int wid = tid >> 6;
    if ((tid & 63) == 0) { ssum[wid] = sum; ssq[wid] = sq; }
    __syncthreads();
    sum = ssum[0] + ssum[1] + ssum[2] + ssum[3];
    sq  = ssq[0] + ssq[1] + ssq[2] + ssq[3];
    const float mean = sum * (1.0f / CD);
    const float var  = sq * (1.0f / CD) - mean * mean;
    const float rstd = rsqrtf(var + 1e-5f);
    float4 gv = *(const float4*)&g[tid * 4];
    float4 bv = *(const float4*)&beta[tid * 4];
    float4 r;
    r.x = (x0 - mean) * rstd * gv.x + bv.x;
    r.y = (x1 - mean) * rstd * gv.y + bv.y;
    r.z = (x2 - mean) * rstd * gv.z + bv.z;
    r.w = (x3 - mean) * rstd * gv.w + bv.w;
    *(float4*)&out[base + tid * 4] = r;
    if (outbf) {
        union { ushort us[4]; uint2 q; } pk;
        pk.us[0] = f2bf(r.x); pk.us[1] = f2bf(r.y); pk.us[2] = f2bf(r.z); pk.us[3] = f2bf(r.w);
        *(uint2*)&outbf[base + tid * 4] = pk.q;
    }
}

extern "C" void kernel_launch(void* const* d_in, const int* in_sizes, int n_in,
                              void* d_out, int out_size, void* d_ws, size_t ws_size,
                              hipStream_t stream) {
    const float* x    = (const float*)d_in[0];
    const float* memL = (const float*)d_in[1];
    const float* Wq   = (const float*)d_in[2];
    const float* Wk   = (const float*)d_in[3];
    const float* Wv   = (const float*)d_in[4];
    const float* Wr   = (const float*)d_in[5];
    const float* Wo   = (const float*)d_in[6];
    const float* rwb  = (const float*)d_in[7];
    const float* rrb  = (const float*)d_in[8];
    const float* ln1g = (const float*)d_in[9];
    const float* ln1b = (const float*)d_in[10];
    const float* ln2g = (const float*)d_in[11];
    const float* ln2b = (const float*)d_in[12];
    const float* W1   = (const float*)d_in[13];
    const float* b1   = (const float*)d_in[14];
    const float* W2   = (const float*)d_in[15];
    const float* b2   = (const float*)d_in[16];

    const size_t MEG = 1048576;
    float* h    = (float*)d_ws;            // 1M f32
    float* tmp  = h + MEG;                 // 1M f32
    float* qb   = tmp + MEG;               // 1M f32
    float* kvo  = qb + MEG;                // 4M f32 (2048x2048)
    float* rb   = kvo + 4 * MEG;           // 1M f32
    ushort* hbf   = (ushort*)(rb + MEG);   // 1M us
    ushort* kvbf  = hbf + MEG;             // 2M us
    ushort* posbf = kvbf + 2 * MEG;        // 1M us
    ushort* attbf = posbf + MEG;           // 1M us
    ushort* ff1bf = attbf + MEG;           // 4M us
    ushort* wbuf  = ff1bf + 4 * MEG;       // 4M us (rotating weight buffer, 8MB)
    // total 58 MB

    const size_t BSD = (size_t)CB * CS * CD;

    hipMemcpyAsync(h, x, BSD * sizeof(float), hipMemcpyDeviceToDevice, stream);
    pos_kernel<<<(CT * (CD / 2)) / 256, 256, 0, stream>>>(posbf);
    cvt_bf16_kernel<<<(BSD / 8) / 256, 256, 0, stream>>>(h, hbf, BSD / 8);

    for (int l = 0; l < CL; ++l) {
        const size_t wofs = (size_t)l * CD * CD;
        concat_bf16_kernel<<<(CB * CT * CD / 8) / 256, 256, 0, stream>>>(
            memL + (size_t)l * CB * CM * CD, h, kvbf);

        // q = (h @ Wq) * 0.125  -> f32
        transpose_cvt<<<dim3(16, 16), 256, 0, stream>>>(Wq + wofs, wbuf, CD, CD);
        gemm_bf16<<<dim3(CD / 128, CB * CS / 128), 256, 0, stream>>>(
            hbf, wbuf, qb, nullptr, CB * CS, CD, CD, nullptr, 0.125f, 0);

        // k|v fused: kv @ [Wk|Wv] -> kvo f32 [2048][2048]
        transpose_cvt<<<dim3(16, 16), 256, 0, stream>>>(Wk + wofs, wbuf, CD, CD);
        transpose_cvt<<<dim3(16, 16), 256, 0, stream>>>(Wv + wofs, wbuf + (size_t)CD * CD, CD, CD);
        gemm_bf16<<<dim3(2 * CD / 128, CB * CT / 128), 256, 0, stream>>>(
            kvbf, wbuf, kvo, nullptr, CB * CT, 2 * CD, CD, nullptr, 1.0f, 0);

        // r = pos @ Wr -> f32
        transpose_cvt<<<dim3(16, 16), 256, 0, stream>>>(Wr + wofs, wbuf, CD, CD);
        gemm_bf16<<<dim3(CD / 128, CT / 128), 256, 0, stream>>>(
            posbf, wbuf, rb, nullptr, CT, CD, CD, nullptr, 1.0f, 0);

        // fused relative attention -> bf16
        attn_kernel<<<dim3(CS / 32, CH, CB), 256, 0, stream>>>(
            qb, kvo, rb, rwb + (size_t)l * CH * CDK, rrb + (size_t)l * CH * CDK, attbf);

        // merge linear + LN1
        transpose_cvt<<<dim3(16, 16), 256, 0, stream>>>(Wo + wofs, wbuf, CD, CD);
        gemm_bf16<<<dim3(CD / 128, CB * CS / 128), 256, 0, stream>>>(
            attbf, wbuf, tmp, nullptr, CB * CS, CD, CD, nullptr, 1.0f, 0);
        ln_kernel<<<CB * CS, 256, 0, stream>>>(
            h, tmp, ln1g + (size_t)l * CD, ln1b + (size_t)l * CD, h, hbf);

        // FF: relu(h@W1+b1)@W2+b2 + LN2
        transpose_cvt<<<dim3(64, 16), 256, 0, stream>>>(W1 + (size_t)l * CD * CFF, wbuf, CD, CFF);
        gemm_bf16<<<dim3(CFF / 128, CB * CS / 128), 256, 0, stream>>>(
            hbf, wbuf, nullptr, ff1bf, CB * CS, CFF, CD, b1 + (size_t)l * CFF, 1.0f, 1);
        transpose_cvt<<<dim3(16, 64), 256, 0, stream>>>(W2 + (size_t)l * CFF * CD, wbuf, CFF, CD);
        gemm_bf16<<<dim3(CD / 128, CB * CS / 128), 256, 0, stream>>>(
            ff1bf, wbuf, tmp, nullptr, CB * CS, CD, CFF, b2 + (size_t)l * CD, 1.0f, 0);
        ln_kernel<<<CB * CS, 256, 0, stream>>>(
            h, tmp, ln2g + (size_t)l * CD, ln2b + (size_t)l * CD, h,
            (l == CL - 1) ? nullptr : hbf);
    }
    hipMemcpyAsync(d_out, h, BSD * sizeof(float), hipMemcpyDeviceToDevice, stream);
}

// Round 3
// 1049.068 us; speedup vs baseline: 4.4503x; 1.6323x over previous
//
#include <hip/hip_runtime.h>
#include <math.h>

// Transformer-XL tower. bf16 MFMA GEMMs + MFMA flash attention.
// L=4, B=2, S=512, M=512, D=1024, H=16, DK=64, FF=4096, T=S+M=1024
#define CB  2
#define CS  512
#define CM  512
#define CD  1024
#define CH  16
#define CDK 64
#define CFF 4096
#define CL  4
#define CT  1024

using short8 = __attribute__((ext_vector_type(8))) short;
using short4v = __attribute__((ext_vector_type(4))) short;
using f32x4  = __attribute__((ext_vector_type(4))) float;

__device__ __forceinline__ ushort f2bf(float x) {
    union { float f; unsigned int u; } c; c.f = x;
    unsigned int u = c.u + 0x7FFFu + ((c.u >> 16) & 1u);
    return (ushort)(u >> 16);
}

// async global->LDS, 16B per lane; dest = wave-uniform base + lane*16
#define GLD16(gsrc, ldst) \
    __builtin_amdgcn_global_load_lds((const __attribute__((address_space(1))) void*)(gsrc), \
                                     (__attribute__((address_space(3))) void*)(ldst), 16, 0, 0)

// ---------------- positional encodings -> bf16 [T][D]
__global__ void pos_kernel(ushort* __restrict__ pos) {
    int idx = blockIdx.x * blockDim.x + threadIdx.x;   // T * D/2
    if (idx >= CT * (CD / 2)) return;
    int i = idx % (CD / 2);
    int t = idx / (CD / 2);
    float p = (float)(CT - 1 - t);
    float inv = __expf(-(float)i * (9.210340371976184f / 512.0f));
    float ang = p * inv;
    pos[(size_t)t * CD + i]          = f2bf(sinf(ang));
    pos[(size_t)t * CD + i + CD / 2] = f2bf(cosf(ang));
}

// ---------------- kv_bf16 = concat(memory[l], h) along time
__global__ void concat_bf16_kernel(const float* __restrict__ mem, const float* __restrict__ h,
                                   ushort* __restrict__ kv) {
    int idx = blockIdx.x * blockDim.x + threadIdx.x;   // B*T*D/8
    const int D8 = CD / 8;
    if (idx >= CB * CT * D8) return;
    int d8 = idx % D8;
    int bt = idx / D8;
    int t = bt % CT;
    int b = bt / CT;
    const float* src = (t < CM) ? &mem[((size_t)(b * CM + t)) * CD + d8 * 8]
                                : &h[((size_t)(b * CS + (t - CM))) * CD + d8 * 8];
    float4 a = *(const float4*)src;
    float4 c = *(const float4*)(src + 4);
    union { ushort us[8]; uint4 q; } pk;
    pk.us[0] = f2bf(a.x); pk.us[1] = f2bf(a.y); pk.us[2] = f2bf(a.z); pk.us[3] = f2bf(a.w);
    pk.us[4] = f2bf(c.x); pk.us[5] = f2bf(c.y); pk.us[6] = f2bf(c.z); pk.us[7] = f2bf(c.w);
    ((uint4*)kv)[idx] = pk.q;
}

// ---------------- elementwise f32 -> bf16 (n8 = count/8)
__global__ void cvt_bf16_kernel(const float* __restrict__ in, ushort* __restrict__ out, int n8) {
    int i = blockIdx.x * blockDim.x + threadIdx.x;
    if (i >= n8) return;
    float4 a = ((const float4*)in)[i * 2];
    float4 c = ((const float4*)in)[i * 2 + 1];
    union { ushort us[8]; uint4 q; } pk;
    pk.us[0] = f2bf(a.x); pk.us[1] = f2bf(a.y); pk.us[2] = f2bf(a.z); pk.us[3] = f2bf(a.w);
    pk.us[4] = f2bf(c.x); pk.us[5] = f2bf(c.y); pk.us[6] = f2bf(c.z); pk.us[7] = f2bf(c.w);
    ((uint4*)out)[i] = pk.q;
}

// ---------------- transpose+convert: in f32 [K][N] -> out bf16 [N][K]
__global__ __launch_bounds__(256)
void transpose_cvt(const float* __restrict__ in, ushort* __restrict__ out, int Kd, int Nc) {
    __shared__ __align__(16) float t[64][68];
    const int n0 = blockIdx.x * 64, k0 = blockIdx.y * 64;
    const int tid = threadIdx.x;
    #pragma unroll
    for (int rep = 0; rep < 4; ++rep) {
        int lin = rep * 256 + tid;         // 64 rows x 16 float4
        int r = lin >> 4, c4 = lin & 15;
        float4 v = *(const float4*)&in[(size_t)(k0 + r) * Nc + n0 + c4 * 4];
        *(float4*)&t[r][c4 * 4] = v;
    }
    __syncthreads();
    #pragma unroll
    for (int rep = 0; rep < 2; ++rep) {
        int lin = rep * 256 + tid;         // 64 n-rows x 8 k-chunks
        int n = lin >> 3, kc = lin & 7;
        union { ushort us[8]; uint4 q; } pk;
        #pragma unroll
        for (int j = 0; j < 8; ++j) pk.us[j] = f2bf(t[kc * 8 + j][n]);
        *(uint4*)&out[(size_t)(n0 + n) * Kd + k0 + kc * 8] = pk.q;
    }
}

// ---------------- bf16 MFMA GEMM: C[M,N] = A[M,K] @ Bt[N,K]^T
// BMxBN tile, BK=32, 4 waves (2x2); wave covers (BM/2)x(BN/2)
template<int BM, int BN>
__global__ __launch_bounds__(256)
void gemm_bf16(const ushort* __restrict__ A, const ushort* __restrict__ Bt,
               float* __restrict__ Cf, ushort* __restrict__ Cbf,
               int Nc, int Kd, const float* __restrict__ bias,
               float scale, int relu)
{
    constexpr int FM = BM / 32, FN = BN / 32;
    __shared__ __align__(16) ushort As[BM * 32];
    __shared__ __align__(16) ushort Bs[BN * 32];
    const int tid  = threadIdx.x;
    const int lane = tid & 63, w = tid >> 6;
    const int wr = w >> 1, wc = w & 1;
    const int row0 = blockIdx.y * BM, col0 = blockIdx.x * BN;
    const ushort* Ab = A  + (size_t)row0 * Kd;
    const ushort* Bb = Bt + (size_t)col0 * Kd;
    f32x4 acc[FM][FN];
    #pragma unroll
    for (int m = 0; m < FM; ++m)
        #pragma unroll
        for (int n = 0; n < FN; ++n) acc[m][n] = (f32x4){0.f, 0.f, 0.f, 0.f};

    for (int k0 = 0; k0 < Kd; k0 += 32) {
        __syncthreads();
        #pragma unroll
        for (int c = 0; c < BM / 64; ++c) {
            const int linw = (c * 4 + w) * 64;
            const int lin  = linw + lane;
            const int row = lin >> 2, kc = lin & 3;
            GLD16(Ab + (size_t)row * Kd + k0 + kc * 8, As + linw * 8);
        }
        #pragma unroll
        for (int c = 0; c < BN / 64; ++c) {
            const int linw = (c * 4 + w) * 64;
            const int lin  = linw + lane;
            const int row = lin >> 2, kc = lin & 3;
            GLD16(Bb + (size_t)row * Kd + k0 + kc * 8, Bs + linw * 8);
        }
        __syncthreads();
        short8 af[FM], bfr[FN];
        #pragma unroll
        for (int m = 0; m < FM; ++m)
            af[m] = *(const short8*)&As[(wr * (BM / 2) + m * 16 + (lane & 15)) * 32 + (lane >> 4) * 8];
        #pragma unroll
        for (int n = 0; n < FN; ++n)
            bfr[n] = *(const short8*)&Bs[(wc * (BN / 2) + n * 16 + (lane & 15)) * 32 + (lane >> 4) * 8];
        #pragma unroll
        for (int m = 0; m < FM; ++m)
            #pragma unroll
            for (int n = 0; n < FN; ++n)
                acc[m][n] = __builtin_amdgcn_mfma_f32_16x16x32_bf16(af[m], bfr[n], acc[m][n], 0, 0, 0);
    }

    const int colbase = col0 + wc * (BN / 2) + (lane & 15);
    const int rowbase = row0 + wr * (BM / 2) + ((lane >> 4) << 2);
    #pragma unroll
    for (int n = 0; n < FN; ++n) {
        const int col = colbase + n * 16;
        const float bv = bias ? bias[col] : 0.f;
        #pragma unroll
        for (int m = 0; m < FM; ++m) {
            #pragma unroll
            for (int r = 0; r < 4; ++r) {
                const int row = rowbase + m * 16 + r;
                float v = acc[m][n][r] * scale + bv;
                if (relu) v = fmaxf(v, 0.f);
                if (Cf)  Cf[(size_t)row * Nc + col] = v;
                if (Cbf) Cbf[(size_t)row * Nc + col] = f2bf(v);
            }
        }
    }
}

// ---------------- MFMA flash rel-attention
// block: 64 q-rows of one (b,h); 4 waves, wave w owns rows [q0+16w, q0+16w+16)
// score(i,j) = (q_i+rwb)·k_j + (q_i+rrb)·r_{j+511-i},  valid j <= i+512
__global__ __launch_bounds__(256)
void attn_kernel(const float* __restrict__ qm, const ushort* __restrict__ kvb,
                 const ushort* __restrict__ rbm,
                 const float* __restrict__ rwb, const float* __restrict__ rrb,
                 ushort* __restrict__ outm)
{
    const int zt = blockIdx.x, hh = blockIdx.y, bb = blockIdx.z;
    const int q0 = zt * 64;
    __shared__ __align__(16) ushort Ks[64][72];     // K rows [j][k]
    __shared__ __align__(16) ushort Vt[64][68];     // V transposed [d][j]
    __shared__ __align__(16) ushort Rs[128][72];    // R band rows [trel-band][k]
    __shared__ __align__(16) ushort Pl[4][16][72];  // per-wave P [i_local][j_local]
    const int tid = threadIdx.x;
    const int lane = tid & 63, w = tid >> 6;
    const int g = lane >> 4, lo4 = lane & 15;

    // Q fragments (A-operand: row = lo4): aqw = q + r_w_bias, aqr = q + r_r_bias
    short8 aqw[2], aqr[2];
    {
        const float* qrow = qm + ((size_t)(bb * CS + q0 + w * 16 + lo4)) * CD + hh * CDK;
        const float* bw = rwb + hh * CDK;
        const float* br = rrb + hh * CDK;
        #pragma unroll
        for (int c = 0; c < 2; ++c) {
            const int kb = c * 32 + g * 8;
            float4 a0 = *(const float4*)&qrow[kb];
            float4 a1 = *(const float4*)&qrow[kb + 4];
            float4 w0 = *(const float4*)&bw[kb];
            float4 w1 = *(const float4*)&bw[kb + 4];
            float4 r0 = *(const float4*)&br[kb];
            float4 r1 = *(const float4*)&br[kb + 4];
            aqw[c][0] = (short)f2bf(a0.x + w0.x); aqw[c][1] = (short)f2bf(a0.y + w0.y);
            aqw[c][2] = (short)f2bf(a0.z + w0.z); aqw[c][3] = (short)f2bf(a0.w + w0.w);
            aqw[c][4] = (short)f2bf(a1.x + w1.x); aqw[c][5] = (short)f2bf(a1.y + w1.y);
            aqw[c][6] = (short)f2bf(a1.z + w1.z); aqw[c][7] = (short)f2bf(a1.w + w1.w);
            aqr[c][0] = (short)f2bf(a0.x + r0.x); aqr[c][1] = (short)f2bf(a0.y + r0.y);
            aqr[c][2] = (short)f2bf(a0.z + r0.z); aqr[c][3] = (short)f2bf(a0.w + r0.w);
            aqr[c][4] = (short)f2bf(a1.x + r1.x); aqr[c][5] = (short)f2bf(a1.y + r1.y);
            aqr[c][6] = (short)f2bf(a1.z + r1.z); aqr[c][7] = (short)f2bf(a1.w + r1.w);
        }
    }

    float mr[4] = {-1e30f, -1e30f, -1e30f, -1e30f};
    float lr[4] = {0.f, 0.f, 0.f, 0.f};
    f32x4 oacc[4];
    #pragma unroll
    for (int n = 0; n < 4; ++n) oacc[n] = (f32x4){0.f, 0.f, 0.f, 0.f};

    const int ntiles = zt + 9;
    for (int tt = 0; tt < ntiles; ++tt) {
        const int j0 = tt * 64;
        const int bandbase = j0 + 448 - q0;     // block band: trel in [bandbase, bandbase+128)
        __syncthreads();
        // ---- stage K: 64 rows x 64 bf16
        #pragma unroll
        for (int rep = 0; rep < 2; ++rep) {
            int task = rep * 256 + tid;
            int row = task >> 3, c8 = task & 7;
            uint4 kq = *(const uint4*)&kvb[((size_t)(bb * CT + j0 + row)) * 2048 + hh * 64 + c8 * 8];
            *(uint4*)&Ks[row][c8 * 8] = kq;
        }
        // ---- stage V transposed: Vt[d][j]
        {
            int jp = tid >> 3, c8 = tid & 7;
            const ushort* vsrc = &kvb[((size_t)(bb * CT + j0 + 2 * jp)) * 2048 + 1024 + hh * 64 + c8 * 8];
            uint4 v0 = *(const uint4*)vsrc;
            uint4 v1 = *(const uint4*)(vsrc + 2048);
            const ushort* pa0 = (const ushort*)&v0;
            const ushort* pa1 = (const ushort*)&v1;
            #pragma unroll
            for (int e = 0; e < 8; ++e)
                *(uint*)&Vt[c8 * 8 + e][2 * jp] = (uint)pa0[e] | ((uint)pa1[e] << 16);
        }
        // ---- stage R band: 128 rows
        #pragma unroll
        for (int rep = 0; rep < 4; ++rep) {
            int task = rep * 256 + tid;
            int row = task >> 3, c8 = task & 7;
            int trel = bandbase + row;
            trel = trel < 0 ? 0 : (trel > CT - 1 ? CT - 1 : trel);
            uint4 rq = *(const uint4*)&rbm[(size_t)trel * CD + hh * 64 + c8 * 8];
            *(uint4*)&Rs[row][c8 * 8] = rq;
        }
        __syncthreads();

        // ---- content: S[m] = (Q+rwb)·K^T  (D: col j16 = lo4, row i = 4g+r)
        f32x4 sa[4];
        #pragma unroll
        for (int m = 0; m < 4; ++m) sa[m] = (f32x4){0.f, 0.f, 0.f, 0.f};
        #pragma unroll
        for (int c = 0; c < 2; ++c)
            #pragma unroll
            for (int m = 0; m < 4; ++m) {
                short8 bk = *(const short8*)&Ks[m * 16 + lo4][c * 32 + g * 8];
                sa[m] = __builtin_amdgcn_mfma_f32_16x16x32_bf16(aqw[c], bk, sa[m], 0, 0, 0);
            }
        // ---- rel: REL[mm] = (Q+rrb)·Rband^T over wave window [48-16w, 128-16w)
        f32x4 ra[5];
        #pragma unroll
        for (int mm = 0; mm < 5; ++mm) ra[mm] = (f32x4){0.f, 0.f, 0.f, 0.f};
        const int wst = 48 - 16 * w;
        #pragma unroll
        for (int c = 0; c < 2; ++c)
            #pragma unroll
            for (int mm = 0; mm < 5; ++mm) {
                short8 brr = *(const short8*)&Rs[wst + mm * 16 + lo4][c * 32 + g * 8];
                ra[mm] = __builtin_amdgcn_mfma_f32_16x16x32_bf16(aqr[c], brr, ra[mm], 0, 0, 0);
            }

        // ---- rel gather (shuffle), mask, online softmax per row r
        #pragma unroll
        for (int r = 0; r < 4; ++r) {
            const int il = 4 * g + r;                    // wave-local row
            const int delta = lo4 + 15 - il;             // in [0,30]
            const int srcl = (lane & 48) | (delta & 15);
            const int hi = delta >> 4;
            float s[4];
            #pragma unroll
            for (int m = 0; m < 4; ++m) {
                float vlo = __shfl(ra[m][r], srcl);
                float vhi = __shfl(ra[m + 1][r], srcl);
                float rel = hi ? vhi : vlo;
                const int jg = j0 + m * 16 + lo4;
                const int ig = q0 + w * 16 + il;
                s[m] = (jg <= ig + CM) ? (sa[m][r] + rel) : -1e30f;
            }
            float tm = fmaxf(fmaxf(s[0], s[1]), fmaxf(s[2], s[3]));
            #pragma unroll
            for (int off = 1; off < 16; off <<= 1) tm = fmaxf(tm, __shfl_xor(tm, off));
            const float mn = fmaxf(mr[r], tm);
            const float scl = __expf(mr[r] - mn);
            mr[r] = mn;
            float ts = 0.f;
            #pragma unroll
            for (int m = 0; m < 4; ++m) {
                float p = __expf(s[m] - mn);
                ts += p;
                Pl[w][il][m * 16 + lo4] = f2bf(p);
            }
            #pragma unroll
            for (int off = 1; off < 16; off <<= 1) ts += __shfl_xor(ts, off);
            lr[r] = lr[r] * scl + ts;
            #pragma unroll
            for (int n = 0; n < 4; ++n) oacc[n][r] *= scl;
        }

        // ---- PV: O += P·V   (A = Pl rows (i=lo4), B = Vt rows (d))
        #pragma unroll
        for (int c = 0; c < 2; ++c) {
            short8 pa = *(const short8*)&Pl[w][lo4][c * 32 + g * 8];
            #pragma unroll
            for (int n = 0; n < 4; ++n) {
                short4v vh0 = *(const short4v*)&Vt[n * 16 + lo4][c * 32 + g * 8];
                short4v vh1 = *(const short4v*)&Vt[n * 16 + lo4][c * 32 + g * 8 + 4];
                short8 vb;
                vb[0] = vh0[0]; vb[1] = vh0[1]; vb[2] = vh0[2]; vb[3] = vh0[3];
                vb[4] = vh1[0]; vb[5] = vh1[1]; vb[6] = vh1[2]; vb[7] = vh1[3];
                oacc[n] = __builtin_amdgcn_mfma_f32_16x16x32_bf16(pa, vb, oacc[n], 0, 0, 0);
            }
        }
    }

    // epilogue: row i = q0+16w+4g+r, col d = n*16+lo4
    #pragma unroll
    for (int r = 0; r < 4; ++r) {
        const float invl = 1.0f / lr[r];
        const int ig = q0 + w * 16 + 4 * g + r;
        ushort* orow = outm + ((size_t)(bb * CS + ig)) * CD + hh * CDK + lo4;
        #pragma unroll
        for (int n = 0; n < 4; ++n)
            orow[n * 16] = f2bf(oacc[n][r] * invl);
    }
}

// ---------------- residual + layernorm, dual output (f32 + optional bf16)
__global__ __launch_bounds__(256)
void ln_kernel(const float* __restrict__ a, const float* __restrict__ bsrc,
               const float* __restrict__ g, const float* __restrict__ beta,
               float* __restrict__ out, ushort* __restrict__ outbf)
{
    const int row = blockIdx.x;
    const int tid = threadIdx.x;
    const size_t base = (size_t)row * CD;
    float4 xa = *(const float4*)&a[base + tid * 4];
    float4 xb = *(const float4*)&bsrc[base + tid * 4];
    float x0 = xa.x + xb.x, x1 = xa.y + xb.y, x2 = xa.z + xb.z, x3 = xa.w + xb.w;
    float sum = x0 + x1 + x2 + x3;
    float sq  = x0 * x0 + x1 * x1 + x2 * x2 + x3 * x3;
    #pragma unroll
    for (int off = 1; off < 64; off <<= 1) {
        sum += __shfl_xor(sum, off);
        sq  += __shfl_xor(sq, off);
    }
    __shared__ float ssum[4], ssq[4];
    const int wid = tid >> 6;
    if ((tid & 63) == 0) { ssum[wid] = sum; ssq[wid] = sq; }
    __syncthreads();
    sum = ssum[0] + ssum[1] + ssum[2] + ssum[3];
    sq  = ssq[0] + ssq[1] + ssq[2] + ssq[3];
    const float mean = sum * (1.0f / CD);
    const float var  = sq * (1.0f / CD) - mean * mean;
    const float rstd = rsqrtf(var + 1e-5f);
    float4 gv = *(const float4*)&g[tid * 4];
    float4 bv = *(const float4*)&beta[tid * 4];
    float4 r;
    r.x = (x0 - mean) * rstd * gv.x + bv.x;
    r.y = (x1 - mean) * rstd * gv.y + bv.y;
    r.z = (x2 - mean) * rstd * gv.z + bv.z;
    r.w = (x3 - mean) * rstd * gv.w + bv.w;
    *(float4*)&out[base + tid * 4] = r;
    if (outbf) {
        union { ushort us[4]; uint2 q; } pk;
        pk.us[0] = f2bf(r.x); pk.us[1] = f2bf(r.y); pk.us[2] = f2bf(r.z); pk.us[3] = f2bf(r.w);
        *(uint2*)&outbf[base + tid * 4] = pk.q;
    }
}

extern "C" void kernel_launch(void* const* d_in, const int* in_sizes, int n_in,
                              void* d_out, int out_size, void* d_ws, size_t ws_size,
                              hipStream_t stream) {
    const float* x    = (const float*)d_in[0];
    const float* memL = (const float*)d_in[1];
    const float* Wq   = (const float*)d_in[2];
    const float* Wk   = (const float*)d_in[3];
    const float* Wv   = (const float*)d_in[4];
    const float* Wr   = (const float*)d_in[5];
    const float* Wo   = (const float*)d_in[6];
    const float* rwb  = (const float*)d_in[7];
    const float* rrb  = (const float*)d_in[8];
    const float* ln1g = (const float*)d_in[9];
    const float* ln1b = (const float*)d_in[10];
    const float* ln2g = (const float*)d_in[11];
    const float* ln2b = (const float*)d_in[12];
    const float* W1   = (const float*)d_in[13];
    const float* b1   = (const float*)d_in[14];
    const float* W2   = (const float*)d_in[15];
    const float* b2   = (const float*)d_in[16];

    const size_t MEG = 1048576;
    float* h    = (float*)d_ws;              // 1M f32
    float* tmp  = h + MEG;                   // 1M f32
    float* qb   = tmp + MEG;                 // 1M f32
    ushort* hbf   = (ushort*)(qb + MEG);     // 1M us
    ushort* kvbf  = hbf + MEG;               // 2M us
    ushort* kvob  = kvbf + 2 * MEG;          // 4M us  (k|v bf16, 2048x2048)
    ushort* rbb   = kvob + 4 * MEG;          // 1M us
    ushort* posbf = rbb + MEG;               // 1M us
    ushort* attbf = posbf + MEG;             // 1M us
    ushort* ff1bf = attbf + MEG;             // 4M us
    ushort* wbuf  = ff1bf + 4 * MEG;         // 4M us (rotating weight buffer)
    // total 48 MB

    const size_t BSD = (size_t)CB * CS * CD;

    hipMemcpyAsync(h, x, BSD * sizeof(float), hipMemcpyDeviceToDevice, stream);
    pos_kernel<<<(CT * (CD / 2)) / 256, 256, 0, stream>>>(posbf);
    cvt_bf16_kernel<<<(BSD / 8) / 256, 256, 0, stream>>>(h, hbf, BSD / 8);

    for (int l = 0; l < CL; ++l) {
        const size_t wofs = (size_t)l * CD * CD;
        concat_bf16_kernel<<<(CB * CT * CD / 8) / 256, 256, 0, stream>>>(
            memL + (size_t)l * CB * CM * CD, h, kvbf);

        // q = (h @ Wq) * 0.125  -> f32
        transpose_cvt<<<dim3(16, 16), 256, 0, stream>>>(Wq + wofs, wbuf, CD, CD);
        gemm_bf16<64, 64><<<dim3(16, 16), 256, 0, stream>>>(
            hbf, wbuf, qb, nullptr, CD, CD, nullptr, 0.125f, 0);

        // k|v fused: kv @ [Wk|Wv] -> bf16 [2048][2048]
        transpose_cvt<<<dim3(16, 16), 256, 0, stream>>>(Wk + wofs, wbuf, CD, CD);
        transpose_cvt<<<dim3(16, 16), 256, 0, stream>>>(Wv + wofs, wbuf + (size_t)CD * CD, CD, CD);
        gemm_bf16<128, 128><<<dim3(16, 16), 256, 0, stream>>>(
            kvbf, wbuf, nullptr, kvob, 2 * CD, CD, nullptr, 1.0f, 0);

        // r = pos @ Wr -> bf16
        transpose_cvt<<<dim3(16, 16), 256, 0, stream>>>(Wr + wofs, wbuf, CD, CD);
        gemm_bf16<64, 64><<<dim3(16, 16), 256, 0, stream>>>(
            posbf, wbuf, nullptr, rbb, CD, CD, nullptr, 1.0f, 0);

        // fused relative attention -> bf16
        attn_kernel<<<dim3(CS / 64, CH, CB), 256, 0, stream>>>(
            qb, kvob, rbb, rwb + (size_t)l * CH * CDK, rrb + (size_t)l * CH * CDK, attbf);

        // merge linear + LN1
        transpose_cvt<<<dim3(16, 16), 256, 0, stream>>>(Wo + wofs, wbuf, CD, CD);
        gemm_bf16<64, 64><<<dim3(16, 16), 256, 0, stream>>>(
            attbf, wbuf, tmp, nullptr, CD, CD, nullptr, 1.0f, 0);
        ln_kernel<<<CB * CS, 256, 0, stream>>>(
            h, tmp, ln1g + (size_t)l * CD, ln1b + (size_t)l * CD, h, hbf);

        // FF: relu(h@W1+b1)@W2+b2 + LN2
        transpose_cvt<<<dim3(64, 16), 256, 0, stream>>>(W1 + (size_t)l * CD * CFF, wbuf, CD, CFF);
        gemm_bf16<128, 128><<<dim3(32, 8), 256, 0, stream>>>(
            hbf, wbuf, nullptr, ff1bf, CFF, CD, b1 + (size_t)l * CFF, 1.0f, 1);
        transpose_cvt<<<dim3(16, 64), 256, 0, stream>>>(W2 + (size_t)l * CFF * CD, wbuf, CFF, CD);
        gemm_bf16<64, 64><<<dim3(16, 16), 256, 0, stream>>>(
            ff1bf, wbuf, tmp, nullptr, CD, CFF, b2 + (size_t)l * CD, 1.0f, 0);
        ln_kernel<<<CB * CS, 256, 0, stream>>>(
            h, tmp, ln2g + (size_t)l * CD, ln2b + (size_t)l * CD, h,
            (l == CL - 1) ? nullptr : hbf);
    }
    hipMemcpyAsync(d_out, h, BSD * sizeof(float), hipMemcpyDeviceToDevice, stream);
}

// Round 4
// 853.787 us; speedup vs baseline: 5.4681x; 1.2287x over previous
//
#include <hip/hip_runtime.h>
#include <math.h>

// Transformer-XL tower. bf16 MFMA GEMMs (2-phase dbuf + swizzle) + MFMA flash attention (T14).
// L=4, B=2, S=512, M=512, D=1024, H=16, DK=64, FF=4096, T=S+M=1024
#define CB  2
#define CS  512
#define CM  512
#define CD  1024
#define CH  16
#define CDK 64
#define CFF 4096
#define CL  4
#define CT  1024

using short8 = __attribute__((ext_vector_type(8))) short;
using short4v = __attribute__((ext_vector_type(4))) short;
using f32x4  = __attribute__((ext_vector_type(4))) float;

__device__ __forceinline__ ushort f2bf(float x) {
    union { float f; unsigned int u; } c; c.f = x;
    unsigned int u = c.u + 0x7FFFu + ((c.u >> 16) & 1u);
    return (ushort)(u >> 16);
}
__device__ __forceinline__ float bf2f(ushort h) {
    union { unsigned int u; float f; } c; c.u = ((unsigned int)h) << 16;
    return c.f;
}

// async global->LDS, 16B per lane; dest = wave-uniform base + lane*16
#define GLD16(gsrc, ldst) \
    __builtin_amdgcn_global_load_lds((const __attribute__((address_space(1))) void*)(gsrc), \
                                     (__attribute__((address_space(3))) void*)(ldst), 16, 0, 0)

// ---------------- positional encodings -> bf16 [T][D]
__global__ void pos_kernel(ushort* __restrict__ pos) {
    int idx = blockIdx.x * blockDim.x + threadIdx.x;   // T * D/2
    if (idx >= CT * (CD / 2)) return;
    int i = idx % (CD / 2);
    int t = idx / (CD / 2);
    float p = (float)(CT - 1 - t);
    float inv = __expf(-(float)i * (9.210340371976184f / 512.0f));
    float ang = p * inv;
    pos[(size_t)t * CD + i]          = f2bf(sinf(ang));
    pos[(size_t)t * CD + i + CD / 2] = f2bf(cosf(ang));
}

// ---------------- kv_bf16 = concat(memory[l], h) along time
__global__ void concat_bf16_kernel(const float* __restrict__ mem, const float* __restrict__ h,
                                   ushort* __restrict__ kv) {
    int idx = blockIdx.x * blockDim.x + threadIdx.x;   // B*T*D/8
    const int D8 = CD / 8;
    if (idx >= CB * CT * D8) return;
    int d8 = idx % D8;
    int bt = idx / D8;
    int t = bt % CT;
    int b = bt / CT;
    const float* src = (t < CM) ? &mem[((size_t)(b * CM + t)) * CD + d8 * 8]
                                : &h[((size_t)(b * CS + (t - CM))) * CD + d8 * 8];
    float4 a = *(const float4*)src;
    float4 c = *(const float4*)(src + 4);
    union { ushort us[8]; uint4 q; } pk;
    pk.us[0] = f2bf(a.x); pk.us[1] = f2bf(a.y); pk.us[2] = f2bf(a.z); pk.us[3] = f2bf(a.w);
    pk.us[4] = f2bf(c.x); pk.us[5] = f2bf(c.y); pk.us[6] = f2bf(c.z); pk.us[7] = f2bf(c.w);
    ((uint4*)kv)[idx] = pk.q;
}

// ---------------- elementwise f32 -> bf16 (n8 = count/8)
__global__ void cvt_bf16_kernel(const float* __restrict__ in, ushort* __restrict__ out, int n8) {
    int i = blockIdx.x * blockDim.x + threadIdx.x;
    if (i >= n8) return;
    float4 a = ((const float4*)in)[i * 2];
    float4 c = ((const float4*)in)[i * 2 + 1];
    union { ushort us[8]; uint4 q; } pk;
    pk.us[0] = f2bf(a.x); pk.us[1] = f2bf(a.y); pk.us[2] = f2bf(a.z); pk.us[3] = f2bf(a.w);
    pk.us[4] = f2bf(c.x); pk.us[5] = f2bf(c.y); pk.us[6] = f2bf(c.z); pk.us[7] = f2bf(c.w);
    ((uint4*)out)[i] = pk.q;
}

// ---------------- transpose+convert: in f32 [K][N] -> out bf16 [N][K], z selects input
__global__ __launch_bounds__(256)
void transpose_cvt3(const float* __restrict__ in0, const float* __restrict__ in1,
                    const float* __restrict__ in2, ushort* __restrict__ out,
                    int Kd, int Nc) {
    const float* in = (blockIdx.z == 0) ? in0 : ((blockIdx.z == 1) ? in1 : in2);
    ushort* o = out + (size_t)blockIdx.z * Kd * Nc;
    __shared__ __align__(16) float t[64][68];
    const int n0 = blockIdx.x * 64, k0 = blockIdx.y * 64;
    const int tid = threadIdx.x;
    #pragma unroll
    for (int rep = 0; rep < 4; ++rep) {
        int lin = rep * 256 + tid;         // 64 rows x 16 float4
        int r = lin >> 4, c4 = lin & 15;
        float4 v = *(const float4*)&in[(size_t)(k0 + r) * Nc + n0 + c4 * 4];
        *(float4*)&t[r][c4 * 4] = v;
    }
    __syncthreads();
    #pragma unroll
    for (int rep = 0; rep < 2; ++rep) {
        int lin = rep * 256 + tid;         // 64 n-rows x 8 k-chunks
        int n = lin >> 3, kc = lin & 7;
        union { ushort us[8]; uint4 q; } pk;
        #pragma unroll
        for (int j = 0; j < 8; ++j) pk.us[j] = f2bf(t[kc * 8 + j][n]);
        *(uint4*)&o[(size_t)(n0 + n) * Kd + k0 + kc * 8] = pk.q;
    }
}

// ---------------- bf16 MFMA GEMM: C[M,N] = A[M,K] @ Bt[N,K]^T
// BMxBN tile, BK=64, 4 waves (2x2); 2-phase dbuf pipeline + T2 XOR swizzle.
// LDS tile layout: [row][BK], chunk kc (16B) at (row, kc) holds global chunk kc^(row&7).
template<int BM, int BN>
__global__ __launch_bounds__(256)
void gemm_bf16(const ushort* __restrict__ A, const ushort* __restrict__ Bt,
               float* __restrict__ Cf, ushort* __restrict__ Cbf,
               int Nc, int Kd, const float* __restrict__ bias,
               float scale, int relu)
{
    constexpr int FM = BM / 32, FN = BN / 32;
    __shared__ __align__(16) ushort As[2][BM * 64];
    __shared__ __align__(16) ushort Bs[2][BN * 64];
    const int tid  = threadIdx.x;
    const int lane = tid & 63, w = tid >> 6;
    const int wr = w >> 1, wc = w & 1;
    const int lo4 = lane & 15, g = lane >> 4;
    const int row0 = blockIdx.y * BM, col0 = blockIdx.x * BN;
    const ushort* Ab = A  + (size_t)row0 * Kd;
    const ushort* Bb = Bt + (size_t)col0 * Kd;
    f32x4 acc[FM][FN];
    #pragma unroll
    for (int m = 0; m < FM; ++m)
        #pragma unroll
        for (int n = 0; n < FN; ++n) acc[m][n] = (f32x4){0.f, 0.f, 0.f, 0.f};

    // stage one BK=64 step: BM*8 chunks of 16B; source chunk pre-swizzled by row&7
#define GSTAGE(buf, kk) do {                                                        \
        _Pragma("unroll")                                                           \
        for (int c = 0; c < BM / 32; ++c) {                                         \
            const int linw = (c * 4 + w) * 64;                                      \
            const int lin  = linw + lane;                                           \
            GLD16(Ab + (size_t)(lin >> 3) * Kd + (kk) + ((lin ^ (lin >> 3)) & 7) * 8, \
                  &As[buf][linw * 8]);                                              \
        }                                                                           \
        _Pragma("unroll")                                                           \
        for (int c = 0; c < BN / 32; ++c) {                                         \
            const int linw = (c * 4 + w) * 64;                                      \
            const int lin  = linw + lane;                                           \
            GLD16(Bb + (size_t)(lin >> 3) * Kd + (kk) + ((lin ^ (lin >> 3)) & 7) * 8, \
                  &Bs[buf][linw * 8]);                                              \
        }                                                                           \
    } while (0)

    GSTAGE(0, 0);
    __syncthreads();          // drains vmcnt(0): buf0 ready
    int cur = 0;
    for (int k0 = 0; k0 < Kd; k0 += 64) {
        if (k0 + 64 < Kd) GSTAGE(cur ^ 1, k0 + 64);   // loads fly during compute
        #pragma unroll
        for (int h2 = 0; h2 < 2; ++h2) {
            short8 af[FM], bfr[FN];
            #pragma unroll
            for (int m = 0; m < FM; ++m) {
                const int ar = wr * (BM / 2) + m * 16 + lo4;
                af[m] = *(const short8*)&As[cur][ar * 64 + ((((h2 << 2) + g) ^ (ar & 7)) << 3)];
            }
            #pragma unroll
            for (int n = 0; n < FN; ++n) {
                const int br = wc * (BN / 2) + n * 16 + lo4;
                bfr[n] = *(const short8*)&Bs[cur][br * 64 + ((((h2 << 2) + g) ^ (br & 7)) << 3)];
            }
            __builtin_amdgcn_s_setprio(1);
            #pragma unroll
            for (int m = 0; m < FM; ++m)
                #pragma unroll
                for (int n = 0; n < FN; ++n)
                    acc[m][n] = __builtin_amdgcn_mfma_f32_16x16x32_bf16(af[m], bfr[n], acc[m][n], 0, 0, 0);
            __builtin_amdgcn_s_setprio(0);
        }
        __syncthreads();      // drains stage loads + all waves done reading cur
        cur ^= 1;
    }
#undef GSTAGE

    const int colbase = col0 + wc * (BN / 2) + lo4;
    const int rowbase = row0 + wr * (BM / 2) + (g << 2);
    #pragma unroll
    for (int n = 0; n < FN; ++n) {
        const int col = colbase + n * 16;
        const float bv = bias ? bias[col] : 0.f;
        #pragma unroll
        for (int m = 0; m < FM; ++m) {
            #pragma unroll
            for (int r = 0; r < 4; ++r) {
                const int row = rowbase + m * 16 + r;
                float v = acc[m][n][r] * scale + bv;
                if (relu) v = fmaxf(v, 0.f);
                if (Cf)  Cf[(size_t)row * Nc + col] = v;
                if (Cbf) Cbf[(size_t)row * Nc + col] = f2bf(v);
            }
        }
    }
}

// ---------------- MFMA flash rel-attention, T14 register prefetch
// block: 64 q-rows of one (b,h); 4 waves, wave w owns rows [q0+16w, q0+16w+16)
// kvproj cols: [0,1024)=q (unscaled), [1024,2048)=k, [2048,3072)=v. Row stride 3072.
__global__ __launch_bounds__(256)
void attn_kernel(const ushort* __restrict__ kvp, const ushort* __restrict__ rbm,
                 const float* __restrict__ rwb, const float* __restrict__ rrb,
                 ushort* __restrict__ outm)
{
    const int zt = blockIdx.x, hh = blockIdx.y, bb = blockIdx.z;
    const int q0 = zt * 64;
    __shared__ __align__(16) ushort Ks[64][72];     // K rows [j][k]
    __shared__ __align__(16) ushort Vt[64][68];     // V transposed [d][j]
    __shared__ __align__(16) ushort Rs[128][72];    // R band rows
    __shared__ __align__(16) ushort Pl[4][16][72];  // per-wave P
    const int tid = threadIdx.x;
    const int lane = tid & 63, w = tid >> 6;
    const int g = lane >> 4, lo4 = lane & 15;

    // Q fragments: q (bf16, *0.125) + biases (f32)
    short8 aqw[2], aqr[2];
    {
        const ushort* qrow = kvp + ((size_t)(bb * CT + CM + q0 + w * 16 + lo4)) * 3072 + hh * CDK;
        const float* bw = rwb + hh * CDK;
        const float* br = rrb + hh * CDK;
        #pragma unroll
        for (int c = 0; c < 2; ++c) {
            const int kb = c * 32 + g * 8;
            uint4 qv = *(const uint4*)&qrow[kb];
            const ushort* qe = (const ushort*)&qv;
            float4 w0 = *(const float4*)&bw[kb];
            float4 w1 = *(const float4*)&bw[kb + 4];
            float4 r0 = *(const float4*)&br[kb];
            float4 r1 = *(const float4*)&br[kb + 4];
            float q0f = bf2f(qe[0]) * 0.125f, q1f = bf2f(qe[1]) * 0.125f;
            float q2f = bf2f(qe[2]) * 0.125f, q3f = bf2f(qe[3]) * 0.125f;
            float q4f = bf2f(qe[4]) * 0.125f, q5f = bf2f(qe[5]) * 0.125f;
            float q6f = bf2f(qe[6]) * 0.125f, q7f = bf2f(qe[7]) * 0.125f;
            aqw[c][0] = (short)f2bf(q0f + w0.x); aqw[c][1] = (short)f2bf(q1f + w0.y);
            aqw[c][2] = (short)f2bf(q2f + w0.z); aqw[c][3] = (short)f2bf(q3f + w0.w);
            aqw[c][4] = (short)f2bf(q4f + w1.x); aqw[c][5] = (short)f2bf(q5f + w1.y);
            aqw[c][6] = (short)f2bf(q6f + w1.z); aqw[c][7] = (short)f2bf(q7f + w1.w);
            aqr[c][0] = (short)f2bf(q0f + r0.x); aqr[c][1] = (short)f2bf(q1f + r0.y);
            aqr[c][2] = (short)f2bf(q2f + r0.z); aqr[c][3] = (short)f2bf(q3f + r0.w);
            aqr[c][4] = (short)f2bf(q4f + r1.x); aqr[c][5] = (short)f2bf(q5f + r1.y);
            aqr[c][6] = (short)f2bf(q6f + r1.z); aqr[c][7] = (short)f2bf(q7f + r1.w);
        }
    }

    // staging thread roles
    const int kr0 = tid >> 3;            // K rows 0..31 (rep0) / +32 (rep1)
    const int c8k = tid & 7;
    const int jp  = tid & 31;            // V j-pair (bank-conflict-free write)
    const int c8v = tid >> 5;
    const ushort* kbase = kvp + ((size_t)bb * CT) * 3072 + 1024 + hh * CDK + c8k * 8;
    const ushort* vbase = kvp + ((size_t)bb * CT) * 3072 + 2048 + hh * CDK + c8v * 8;
    const ushort* rbase = rbm + hh * CDK + c8k * 8;

    uint4 rK[2], rV[2], rR[4];
#define LOAD_TILE(TT) do {                                                       \
        const int j0n = (TT) * 64;                                               \
        rK[0] = *(const uint4*)(kbase + (size_t)(j0n + kr0) * 3072);             \
        rK[1] = *(const uint4*)(kbase + (size_t)(j0n + 32 + kr0) * 3072);        \
        rV[0] = *(const uint4*)(vbase + (size_t)(j0n + 2 * jp) * 3072);          \
        rV[1] = *(const uint4*)(vbase + (size_t)(j0n + 2 * jp + 1) * 3072);      \
        const int bnd = j0n + 448 - q0;                                          \
        _Pragma("unroll")                                                        \
        for (int rep = 0; rep < 4; ++rep) {                                      \
            int trel = bnd + rep * 32 + kr0;                                     \
            trel = trel < 0 ? 0 : (trel > CT - 1 ? CT - 1 : trel);               \
            rR[rep] = *(const uint4*)(rbase + (size_t)trel * CD);                \
        }                                                                        \
    } while (0)

    float mr[4] = {-1e30f, -1e30f, -1e30f, -1e30f};
    float lr[4] = {0.f, 0.f, 0.f, 0.f};
    f32x4 oacc[4];
    #pragma unroll
    for (int n = 0; n < 4; ++n) oacc[n] = (f32x4){0.f, 0.f, 0.f, 0.f};

    const int ntiles = zt + 9;
    LOAD_TILE(0);
    for (int tt = 0; tt < ntiles; ++tt) {
        const int j0 = tt * 64;
        __syncthreads();                  // prev compute done with LDS
        // regs -> LDS
        *(uint4*)&Ks[kr0][c8k * 8]      = rK[0];
        *(uint4*)&Ks[32 + kr0][c8k * 8] = rK[1];
        {
            const ushort* p0 = (const ushort*)&rV[0];
            const ushort* p1 = (const ushort*)&rV[1];
            #pragma unroll
            for (int e = 0; e < 8; ++e)
                *(uint*)&Vt[c8v * 8 + e][2 * jp] = (uint)p0[e] | ((uint)p1[e] << 16);
        }
        #pragma unroll
        for (int rep = 0; rep < 4; ++rep)
            *(uint4*)&Rs[rep * 32 + kr0][c8k * 8] = rR[rep];
        __syncthreads();                  // LDS visible
        if (tt + 1 < ntiles) LOAD_TILE(tt + 1);   // overlap next loads with compute

        // ---- content: S = (Q+rwb)·K^T
        f32x4 sa[4];
        #pragma unroll
        for (int m = 0; m < 4; ++m) sa[m] = (f32x4){0.f, 0.f, 0.f, 0.f};
        __builtin_amdgcn_s_setprio(1);
        #pragma unroll
        for (int c = 0; c < 2; ++c)
            #pragma unroll
            for (int m = 0; m < 4; ++m) {
                short8 bk = *(const short8*)&Ks[m * 16 + lo4][c * 32 + g * 8];
                sa[m] = __builtin_amdgcn_mfma_f32_16x16x32_bf16(aqw[c], bk, sa[m], 0, 0, 0);
            }
        // ---- rel: over wave band window [48-16w, 128-16w)
        f32x4 ra[5];
        #pragma unroll
        for (int mm = 0; mm < 5; ++mm) ra[mm] = (f32x4){0.f, 0.f, 0.f, 0.f};
        const int wst = 48 - 16 * w;
        #pragma unroll
        for (int c = 0; c < 2; ++c)
            #pragma unroll
            for (int mm = 0; mm < 5; ++mm) {
                short8 brr = *(const short8*)&Rs[wst + mm * 16 + lo4][c * 32 + g * 8];
                ra[mm] = __builtin_amdgcn_mfma_f32_16x16x32_bf16(aqr[c], brr, ra[mm], 0, 0, 0);
            }
        __builtin_amdgcn_s_setprio(0);

        // ---- rel gather (shuffle), mask, online softmax per row r
        #pragma unroll
        for (int r = 0; r < 4; ++r) {
            const int il = 4 * g + r;
            const int delta = lo4 + 15 - il;
            const int srcl = (lane & 48) | (delta & 15);
            const int hi = delta >> 4;
            float s[4];
            #pragma unroll
            for (int m = 0; m < 4; ++m) {
                float vlo = __shfl(ra[m][r], srcl);
                float vhi = __shfl(ra[m + 1][r], srcl);
                float rel = hi ? vhi : vlo;
                const int jg = j0 + m * 16 + lo4;
                const int ig = q0 + w * 16 + il;
                s[m] = (jg <= ig + CM) ? (sa[m][r] + rel) : -1e30f;
            }
            float tm = fmaxf(fmaxf(s[0], s[1]), fmaxf(s[2], s[3]));
            #pragma unroll
            for (int off = 1; off < 16; off <<= 1) tm = fmaxf(tm, __shfl_xor(tm, off));
            const float mn = fmaxf(mr[r], tm);
            const float scl = __expf(mr[r] - mn);
            mr[r] = mn;
            float ts = 0.f;
            #pragma unroll
            for (int m = 0; m < 4; ++m) {
                float p = __expf(s[m] - mn);
                ts += p;
                Pl[w][il][m * 16 + lo4] = f2bf(p);
            }
            #pragma unroll
            for (int off = 1; off < 16; off <<= 1) ts += __shfl_xor(ts, off);
            lr[r] = lr[r] * scl + ts;
            #pragma unroll
            for (int n = 0; n < 4; ++n) oacc[n][r] *= scl;
        }

        // ---- PV: O += P·V
        __builtin_amdgcn_s_setprio(1);
        #pragma unroll
        for (int c = 0; c < 2; ++c) {
            short8 pa = *(const short8*)&Pl[w][lo4][c * 32 + g * 8];
            #pragma unroll
            for (int n = 0; n < 4; ++n) {
                short4v vh0 = *(const short4v*)&Vt[n * 16 + lo4][c * 32 + g * 8];
                short4v vh1 = *(const short4v*)&Vt[n * 16 + lo4][c * 32 + g * 8 + 4];
                short8 vb;
                vb[0] = vh0[0]; vb[1] = vh0[1]; vb[2] = vh0[2]; vb[3] = vh0[3];
                vb[4] = vh1[0]; vb[5] = vh1[1]; vb[6] = vh1[2]; vb[7] = vh1[3];
                oacc[n] = __builtin_amdgcn_mfma_f32_16x16x32_bf16(pa, vb, oacc[n], 0, 0, 0);
            }
        }
        __builtin_amdgcn_s_setprio(0);
    }
#undef LOAD_TILE

    #pragma unroll
    for (int r = 0; r < 4; ++r) {
        const float invl = 1.0f / lr[r];
        const int ig = q0 + w * 16 + 4 * g + r;
        ushort* orow = outm + ((size_t)(bb * CS + ig)) * CD + hh * CDK + lo4;
        #pragma unroll
        for (int n = 0; n < 4; ++n)
            orow[n * 16] = f2bf(oacc[n][r] * invl);
    }
}

// ---------------- residual + layernorm, dual output (f32 + optional bf16)
__global__ __launch_bounds__(256)
void ln_kernel(const float* __restrict__ a, const float* __restrict__ bsrc,
               const float* __restrict__ g, const float* __restrict__ beta,
               float* __restrict__ out, ushort* __restrict__ outbf)
{
    const int row = blockIdx.x;
    const int tid = threadIdx.x;
    const size_t base = (size_t)row * CD;
    float4 xa = *(const float4*)&a[base + tid * 4];
    float4 xb = *(const float4*)&bsrc[base + tid * 4];
    float x0 = xa.x + xb.x, x1 = xa.y + xb.y, x2 = xa.z + xb.z, x3 = xa.w + xb.w;
    float sum = x0 + x1 + x2 + x3;
    float sq  = x0 * x0 + x1 * x1 + x2 * x2 + x3 * x3;
    #pragma unroll
    for (int off = 1; off < 64; off <<= 1) {
        sum += __shfl_xor(sum, off);
        sq  += __shfl_xor(sq, off);
    }
    __shared__ float ssum[4], ssq[4];
    const int wid = tid >> 6;
    if ((tid & 63) == 0) { ssum[wid] = sum; ssq[wid] = sq; }
    __syncthreads();
    sum = ssum[0] + ssum[1] + ssum[2] + ssum[3];
    sq  = ssq[0] + ssq[1] + ssq[2] + ssq[3];
    const float mean = sum * (1.0f / CD);
    const float var  = sq * (1.0f / CD) - mean * mean;
    const float rstd = rsqrtf(var + 1e-5f);
    float4 gv = *(const float4*)&g[tid * 4];
    float4 bv = *(const float4*)&beta[tid * 4];
    float4 r;
    r.x = (x0 - mean) * rstd * gv.x + bv.x;
    r.y = (x1 - mean) * rstd * gv.y + bv.y;
    r.z = (x2 - mean) * rstd * gv.z + bv.z;
    r.w = (x3 - mean) * rstd * gv.w + bv.w;
    *(float4*)&out[base + tid * 4] = r;
    if (outbf) {
        union { ushort us[4]; uint2 q; } pk;
        pk.us[0] = f2bf(r.x); pk.us[1] = f2bf(r.y); pk.us[2] = f2bf(r.z); pk.us[3] = f2bf(r.w);
        *(uint2*)&outbf[base + tid * 4] = pk.q;
    }
}

extern "C" void kernel_launch(void* const* d_in, const int* in_sizes, int n_in,
                              void* d_out, int out_size, void* d_ws, size_t ws_size,
                              hipStream_t stream) {
    const float* x    = (const float*)d_in[0];
    const float* memL = (const float*)d_in[1];
    const float* Wq   = (const float*)d_in[2];
    const float* Wk   = (const float*)d_in[3];
    const float* Wv   = (const float*)d_in[4];
    const float* Wr   = (const float*)d_in[5];
    const float* Wo   = (const float*)d_in[6];
    const float* rwb  = (const float*)d_in[7];
    const float* rrb  = (const float*)d_in[8];
    const float* ln1g = (const float*)d_in[9];
    const float* ln1b = (const float*)d_in[10];
    const float* ln2g = (const float*)d_in[11];
    const float* ln2b = (const float*)d_in[12];
    const float* W1   = (const float*)d_in[13];
    const float* b1   = (const float*)d_in[14];
    const float* W2   = (const float*)d_in[15];
    const float* b2   = (const float*)d_in[16];

    const size_t MEG = 1048576;
    float* h      = (float*)d_ws;                 // 1M f32
    float* tmp    = h + MEG;                      // 1M f32
    ushort* hbf   = (ushort*)(tmp + MEG);         // 1M us
    ushort* kvbf  = hbf + MEG;                    // 2M us
    ushort* kvproj= kvbf + 2 * MEG;               // 6M us (2048 x 3072)
    ushort* rbb   = kvproj + 6 * MEG;             // 1M us
    ushort* posbf = rbb + MEG;                    // 1M us
    ushort* attbf = posbf + MEG;                  // 1M us
    ushort* ff1bf = attbf + MEG;                  // 4M us
    ushort* wbuf  = ff1bf + 4 * MEG;              // 5M us rotating
    ushort* wbuf3 = wbuf + 3 * MEG;               // Wr^T | Wo^T region
    // total 50 MB

    const size_t BSD = (size_t)CB * CS * CD;

    hipMemcpyAsync(h, x, BSD * sizeof(float), hipMemcpyDeviceToDevice, stream);
    pos_kernel<<<(CT * (CD / 2)) / 256, 256, 0, stream>>>(posbf);
    cvt_bf16_kernel<<<(BSD / 8) / 256, 256, 0, stream>>>(h, hbf, BSD / 8);

    for (int l = 0; l < CL; ++l) {
        const size_t wofs = (size_t)l * CD * CD;
        concat_bf16_kernel<<<(CB * CT * CD / 8) / 256, 256, 0, stream>>>(
            memL + (size_t)l * CB * CM * CD, h, kvbf);

        // [Wq|Wk|Wv]^T -> wbuf[0..3M)
        transpose_cvt3<<<dim3(16, 16, 3), 256, 0, stream>>>(
            Wq + wofs, Wk + wofs, Wv + wofs, wbuf, CD, CD);
        // kvproj = kv @ [Wq|Wk|Wv]  -> bf16 [2048 x 3072]
        gemm_bf16<128, 128><<<dim3(24, 16), 256, 0, stream>>>(
            kvbf, wbuf, nullptr, kvproj, 3 * CD, CD, nullptr, 1.0f, 0);

        // [Wr|Wo]^T -> wbuf3
        transpose_cvt3<<<dim3(16, 16, 2), 256, 0, stream>>>(
            Wr + wofs, Wo + wofs, Wo + wofs, wbuf3, CD, CD);
        // r = pos @ Wr -> bf16
        gemm_bf16<64, 64><<<dim3(16, 16), 256, 0, stream>>>(
            posbf, wbuf3, nullptr, rbb, CD, CD, nullptr, 1.0f, 0);

        // fused relative attention -> bf16
        attn_kernel<<<dim3(CS / 64, CH, CB), 256, 0, stream>>>(
            kvproj, rbb, rwb + (size_t)l * CH * CDK, rrb + (size_t)l * CH * CDK, attbf);

        // merge linear + LN1
        gemm_bf16<64, 64><<<dim3(16, 16), 256, 0, stream>>>(
            attbf, wbuf3 + (size_t)CD * CD, tmp, nullptr, CD, CD, nullptr, 1.0f, 0);
        ln_kernel<<<CB * CS, 256, 0, stream>>>(
            h, tmp, ln1g + (size_t)l * CD, ln1b + (size_t)l * CD, h, hbf);

        // FF: relu(h@W1+b1)@W2+b2 + LN2
        transpose_cvt3<<<dim3(64, 16, 1), 256, 0, stream>>>(
            W1 + (size_t)l * CD * CFF, W1, W1, wbuf, CD, CFF);
        gemm_bf16<128, 128><<<dim3(32, 8), 256, 0, stream>>>(
            hbf, wbuf, nullptr, ff1bf, CFF, CD, b1 + (size_t)l * CFF, 1.0f, 1);
        transpose_cvt3<<<dim3(16, 64, 1), 256, 0, stream>>>(
            W2 + (size_t)l * CFF * CD, W2, W2, wbuf, CFF, CD);
        gemm_bf16<64, 64><<<dim3(16, 16), 256, 0, stream>>>(
            ff1bf, wbuf, tmp, nullptr, CD, CFF, b2 + (size_t)l * CD, 1.0f, 0);
        ln_kernel<<<CB * CS, 256, 0, stream>>>(
            h, tmp, ln2g + (size_t)l * CD, ln2b + (size_t)l * CD, h,
            (l == CL - 1) ? nullptr : hbf);
    }
    hipMemcpyAsync(d_out, h, BSD * sizeof(float), hipMemcpyDeviceToDevice, stream);
}